// Round 19
// baseline (303.664 us; speedup 1.0000x reference)
//
#include <hip/hip_runtime.h>

#define DEV static __device__ __forceinline__

constexpr int BATCH = 256;

DEV float leakyf(float x){ return x > 0.f ? x : 0.2f * x; }

typedef _Float16 f16x8 __attribute__((ext_vector_type(8)));
typedef float f32x4 __attribute__((ext_vector_type(4)));

// ------- pack OIHW conv weights into MFMA B-fragment order, single fp16 -----
template<int IC,int OC>
__global__ __launch_bounds__(256) void wpackM_k(const float* __restrict__ w,
    _Float16* __restrict__ wp){
  constexpr int S = IC/32, F = OC/16;
  int i = blockIdx.x*256 + threadIdx.x;
  if (i >= 9*S*F*512) return;
  int j = i & 7, L = (i >> 3) & 63, rest = i >> 9;
  int f = rest % F; int q2 = rest / F; int s = q2 % S; int t = q2 / S;
  int oc = f*16 + (L & 15), ic = s*32 + (L >> 4)*8 + j;
  wp[i] = (_Float16)w[((size_t)oc*IC + ic)*9 + t];
}

// ------- pack strided-conv weights (IC=16), single fp16 ---------------------
template<int OC,int K>
__global__ __launch_bounds__(256) void wpackS_k(const float* __restrict__ w,
    _Float16* __restrict__ wp){
  constexpr int F = OC/16, KWP = (K+1)/2;
  int i = blockIdx.x*256 + threadIdx.x;
  if (i >= K*KWP*F*512) return;
  int j = i & 7, L = (i >> 3) & 63, rest = i >> 9;
  int f = rest % F, s = rest / F;
  int kh = s / KWP, kwp = s % KWP;
  int k = (L >> 4)*8 + j;
  int kw = 2*kwp + (k >> 4), ic = k & 15;
  int oc = f*16 + (L & 15);
  float v = (kw < K) ? w[((size_t)(oc*16 + ic)*K + kh)*K + kw] : 0.f;
  wp[i] = (_Float16)v;
}

// ------- pack scout1(k7) + conv1(k3) weights, space-to-depth, single fp16 ---
__global__ __launch_bounds__(256) void wpackF_k(const float* __restrict__ sw1,
    const float* __restrict__ tw1, _Float16* __restrict__ wp){
  int i = blockIdx.x*256 + threadIdx.x;
  if (i >= 6*2*512) return;
  int j = i & 7, L = (i >> 3) & 63, rest = i >> 9;
  int nf = rest & 1, s = rest >> 1;
  int k = s*32 + (L >> 4)*8 + j;
  int oc = L & 15;
  int t = k / 48, c = k % 48;
  int dr = (t >> 1) - 1, dc = (t & 1) - 1;
  int ic = c >> 4, pr = (c >> 2) & 3, pc = c & 3;
  float v = 0.f;
  if (nf == 0){
    int kh = 4*dr + pr + 3, kw = 4*dc + pc + 3;
    if (kh >= 0 && kh < 7 && kw >= 0 && kw < 7) v = sw1[((oc*3 + ic)*7 + kh)*7 + kw];
  } else {
    int kh = 4*dr + pr + 1, kw = 4*dc + pc + 1;
    if (kh >= 0 && kh < 3 && kw >= 0 && kw < 3) v = tw1[((oc*3 + ic)*3 + kh)*3 + kw];
  }
  wp[i] = (_Float16)v;
}

// ------- pack expert GEMM weights W[e][N][K] into frag order, single fp16 ---
template<int KTOT>
__global__ __launch_bounds__(256) void wpackGh_k(const float* __restrict__ w, int N,
    _Float16* __restrict__ wp){
  const int NF = N >> 4, KT = KTOT >> 5;
  const int total = NF * KT * 512;
  const int e = blockIdx.y;
  w  += (size_t)e * N * KTOT;
  wp += (size_t)e * total;
  int i = blockIdx.x*256 + threadIdx.x;
  if (i >= total) return;
  int j = i & 7, L = (i >> 3) & 63, rest = i >> 9;
  int nf = rest % NF, t = rest / NF;
  int n = nf*16 + (L & 15), k = t*32 + (L >> 4)*8 + j;
  wp[i] = (_Float16)w[(size_t)n*KTOT + k];
}

// ------- convert fp32 array to fp16 ----------------------------------------
__global__ __launch_bounds__(256) void acvt_k(const float* __restrict__ in,
    _Float16* __restrict__ o16, int nelem){
  int i = blockIdx.x*256 + threadIdx.x;
  if (i >= nelem) return;
  o16[i] = (_Float16)in[i];
}

// ---------- fused scout1+conv1, space-to-depth MFMA fp16, SINGLE barrier ----
// Staging strength-reduced: m = lane (pow2), rc wave-uniform incremental
// (rc = 3*ridx + ic, rc += 4 per pass) -> all row indices in SGPRs.
__global__ __launch_bounds__(256) void fusedM_k(
    const float* __restrict__ x,
    const _Float16* __restrict__ W,
    const float* __restrict__ sb, const float* __restrict__ cb_,
    const float* __restrict__ g, const float* __restrict__ bt,
    const float* __restrict__ mn, const float* __restrict__ vr,
    _Float16* __restrict__ s1out, _Float16* __restrict__ c1out){
  __shared__ __align__(16) _Float16 Ah[3*58*64];
  const int tid = threadIdx.x;
  const int n = blockIdx.x / 28, oh0 = (blockIdx.x % 28) * 2;

  // zero border cols 0 and 57 (full 128B slots)
  if (tid < 48){
    int rr = tid >> 4, side = (tid >> 3) & 1, q = tid & 7;
    int col = side ? 57 : 0;
    *(int4*)((char*)Ah + (((rr*58 + col) << 7) + q*16)) = (int4){0,0,0,0};
  }

  // stage 36 (ic,ridx) groups x 56 float4-cols; 9 passes, rc = (tid>>6)+4*j
  {
    const int m = tid & 63;
    const bool mok = (m < 56);
    const int cc = m + 1;
    int rc0 = tid >> 6;                       // wave-uniform 0..3
    int ic   = (rc0 == 3) ? 0 : rc0;
    int ridx = (rc0 == 3) ? 1 : 0;
    #pragma unroll
    for (int j = 0; j < 9; ++j){
      const int ih = 4*oh0 - 4 + ridx;
      if (mok){
        float4 v = {0.f,0.f,0.f,0.f};
        if (ih >= 0)
          v = *(const float4*)(x + ((size_t)(n*3 + ic)*224 + ih)*224 + 4*m);
        const int rr = ridx >> 2, pr = ridx & 3;
        int boff = (((rr*58 + cc) << 7) + ic*32 + pr*8) ^ ((cc & 7) << 4);
        _Float16 h4[4] = {(_Float16)v.x, (_Float16)v.y, (_Float16)v.z, (_Float16)v.w};
        *(unsigned long long*)((char*)Ah + boff) = *(unsigned long long*)h4;
      }
      ic += 1; ridx += 1;
      if (ic >= 3){ ic -= 3; ridx += 1; }
    }
  }
  __syncthreads();

  const int wid = tid >> 6, lane = tid & 63;
  const int kg8 = (lane >> 4) * 8;
  f32x4 acc[2][2];
  #pragma unroll
  for (int mi = 0; mi < 2; ++mi)
    #pragma unroll
    for (int nf = 0; nf < 2; ++nf) acc[mi][nf] = (f32x4){0.f,0.f,0.f,0.f};

  #pragma unroll
  for (int s = 0; s < 6; ++s){
    const int kk = s*32 + kg8;
    const int t = kk / 48, c0 = kk - t*48;
    const int ra = t >> 1, ca = t & 1;
    f16x8 ah[2];
    #pragma unroll
    for (int mi = 0; mi < 2; ++mi){
      const int m = 2*wid + mi;
      const int rowsel = m >> 2;
      const int ow = (m & 3)*16 + (lane & 15);
      const int owc = ow > 55 ? 55 : ow;
      const int col = owc + ca;
      const int bidx = ((((rowsel + ra)*58 + col) << 7) + c0*2) ^ ((col & 7) << 4);
      ah[mi] = *(const f16x8*)((const char*)Ah + bidx);
    }
    #pragma unroll
    for (int nf = 0; nf < 2; ++nf){
      const f16x8 bw = *(const f16x8*)(W + (s*2 + nf)*512 + lane*8);
      #pragma unroll
      for (int mi = 0; mi < 2; ++mi)
        acc[mi][nf] = __builtin_amdgcn_mfma_f32_16x16x32_f16(ah[mi], bw, acc[mi][nf], 0,0,0);
    }
  }

  const int oc = lane & 15;
  const float sbv = sb[oc];
  const float scv = g[oc] * __frsqrt_rn(vr[oc] + 1e-5f);
  const float mnv = mn[oc], btv = bt[oc], cbv = cb_[oc];
  #pragma unroll
  for (int mi = 0; mi < 2; ++mi){
    const int m = 2*wid + mi;
    const int row = oh0 + (m >> 2);
    const int owb = (m & 3)*16 + (lane >> 4)*4;
    #pragma unroll
    for (int r = 0; r < 4; ++r){
      const int ow = owb + r;
      if (ow >= 56) continue;
      float vs = acc[mi][0][r] + sbv;
      vs = fmaxf((vs - mnv)*scv + btv, 0.f);
      const size_t o = (((size_t)n*56 + row)*56 + ow)*16 + oc;
      s1out[o] = (_Float16)vs;
      c1out[o] = (_Float16)leakyf(acc[mi][1][r] + cbv);
    }
  }
}

// ---------------- strided (S=2) MFMA conv, fp16 NHWC input [B,IH,IW,16] -----
// GATE: fuse BN+relu then spatial-sum -> atomicAdd gsum[n*32+oc] (no tensor out)
template<int OC,int K,int P,int IH,int IW,int ACT,bool OUT16,bool GATE>
__global__ __launch_bounds__(256) void convS_k(
    const _Float16* __restrict__ in,
    const _Float16* __restrict__ W,
    const float* __restrict__ bias,
    const float* __restrict__ bng, const float* __restrict__ bnb,
    const float* __restrict__ bnm, const float* __restrict__ bnv,
    float* __restrict__ outF, _Float16* __restrict__ outH,
    float* __restrict__ gsum){
  constexpr int F = OC/16, KWP = (K+1)/2;
  __shared__ __align__(16) _Float16 A[K*60*16];
  __shared__ float gred[32];

  const int tid = threadIdx.x;
  const int n = blockIdx.x / 28, oh = blockIdx.x % 28;

  if (GATE && tid < 32) gred[tid] = 0.f;

  for (int i = tid; i < K*60*2; i += 256){
    int half = i & 1; int p = i >> 1;
    int c = p % 60; int r = p / 60;
    int ih = 2*oh - P + r, iw = c - P;
    int4 v = {0,0,0,0};
    if (ih >= 0 && ih < IH && iw >= 0 && iw < IW)
      v = *(const int4*)(in + (((size_t)n*IH + ih)*IW + iw)*16 + half*8);
    int byte = ((r*60 + c)*32 + half*16) ^ (((c>>1)&7) << 4);
    *(int4*)((char*)A + byte) = v;
  }
  __syncthreads();

  const int wid = tid >> 6, lane = tid & 63;
  const int fsel = wid & 1, mb = wid >> 1;
  const int ow_l = min(mb*16 + (lane & 15), 27);
  const int ic0b = ((lane >> 4) & 1) * 16;
  const int kwo  = (lane >> 4) >> 1;

  f32x4 acc = {0.f,0.f,0.f,0.f};
  #pragma unroll
  for (int kh = 0; kh < K; ++kh){
    #pragma unroll
    for (int kwp = 0; kwp < KWP; ++kwp){
      const int kw = 2*kwp + kwo;
      const int c = 2*ow_l + kw;
      int byte = ((kh*60 + c)*32 + ic0b) ^ (((c>>1)&7) << 4);
      f16x8 a = *(const f16x8*)((const char*)A + byte);
      const int s = kh*KWP + kwp;
      const f16x8 b = *(const f16x8*)(W + (s*F + fsel)*512 + lane*8);
      acc = __builtin_amdgcn_mfma_f32_16x16x32_f16(a, b, acc, 0,0,0);
    }
  }

  const int oc = fsel*16 + (lane & 15);
  float bv = bias[oc], sc = 1.f, mm = 0.f, bb = 0.f;
  if (ACT == 1){
    sc = bng[oc] * __frsqrt_rn(bnv[oc] + 1e-5f);
    mm = bnm[oc]; bb = bnb[oc];
  }
  float lsum = 0.f;
  #pragma unroll
  for (int r = 0; r < 4; ++r){
    const int ow = mb*16 + (lane >> 4)*4 + r;
    if (ow >= 28) continue;
    float v = acc[r] + bv;
    if (ACT == 1) v = fmaxf((v - mm)*sc + bb, 0.f);
    else          v = leakyf(v);
    if (GATE){
      lsum += v;
    } else {
      const size_t o = (((size_t)n*28 + oh)*28 + ow)*OC + oc;
      if (OUT16) outH[o] = (_Float16)v;
      else       outF[o] = v;
    }
  }
  if (GATE){
    atomicAdd(&gred[oc], lsum);
    __syncthreads();
    if (tid < 32) atomicAdd(&gsum[n*32 + tid], gred[tid]);
  }
}

// ---------------- MFMA single-fp16 3x3 s1 p1 conv on 27x27, padded NHWC -----
template<int IC,int OC,int OUTM>
__global__ __launch_bounds__(256) void convM_k(
    const _Float16* __restrict__ Ag,
    const _Float16* __restrict__ W,
    const float* __restrict__ bias,
    _Float16* __restrict__ OutPad, _Float16* __restrict__ OutNP)
{
  constexpr int S = IC/32, FTOT = OC/16, FW = FTOT/2;
  constexpr int ICB = IC*2, ICG = ICB/16;
  __shared__ __align__(16) char A[4*34*ICB];

  const int tid = threadIdx.x;
  const int bx = blockIdx.x;
  const int n = bx / 14, pr = bx % 14;
  const int oh0 = pr * 2;

  const size_t gbase = ((size_t)n*29) * 29 * IC;
  for (int g = tid; g < 4*34*ICG; g += 256){
    int r = g / (34*ICG);
    int rem = g - r*(34*ICG);
    int c = rem / ICG, q = rem - c*ICG;
    int rp = oh0 + r;
    int4 v = {0,0,0,0};
    if (rp <= 28 && c < 29){
      size_t e = gbase + ((size_t)rp*29 + c)*IC + q*8;
      v = *(const int4*)(Ag + e);
    }
    int off = (r*34 + c)*ICB + q*16;
    int swz = off ^ ((c & 7) << 4);
    *(int4*)(A + swz) = v;
  }
  __syncthreads();

  const int wid = tid >> 6, lane = tid & 63;
  const int rsel = wid & 1, ocq = wid >> 1;
  const int c0 = lane & 15, kg = (lane >> 4) * 16;
  const int colb0 = c0*ICB + kg, colb1 = (16 + c0)*ICB + kg;
  int msk[3];
  #pragma unroll
  for (int kw = 0; kw < 3; ++kw) msk[kw] = ((c0 + kw) & 7) << 4;

  f32x4 acc[2][FW];
  #pragma unroll
  for (int m = 0; m < 2; ++m)
    #pragma unroll
    for (int f = 0; f < FW; ++f) acc[m][f] = (f32x4){0.f,0.f,0.f,0.f};

  #pragma unroll
  for (int kh = 0; kh < 3; ++kh){
    #pragma unroll
    for (int kw = 0; kw < 3; ++kw){
      #pragma unroll
      for (int s = 0; s < S; ++s){
        const int fr0 = (((kh*3 + kw)*S + s)*FTOT + ocq*FW) * 512 + lane*8;
        f16x8 b[FW];
        #pragma unroll
        for (int f = 0; f < FW; ++f)
          b[f] = *(const f16x8*)(W + fr0 + f*512);
        const int base = ((rsel + kh)*34 + kw)*ICB + s*64;
        const int o0 = (base + colb0) ^ msk[kw];
        const int o1 = (base + colb1) ^ msk[kw];
        f16x8 a0 = *(const f16x8*)(A + o0);
        f16x8 a1 = *(const f16x8*)(A + o1);
        #pragma unroll
        for (int f = 0; f < FW; ++f){
          acc[0][f] = __builtin_amdgcn_mfma_f32_16x16x32_f16(a0, b[f], acc[0][f], 0,0,0);
          acc[1][f] = __builtin_amdgcn_mfma_f32_16x16x32_f16(a1, b[f], acc[1][f], 0,0,0);
        }
      }
    }
  }

  const int orow = oh0 + rsel;
  if (orow >= 27) return;
  #pragma unroll
  for (int f = 0; f < FW; ++f){
    const int oc = (ocq*FW + f)*16 + c0;
    const float bv = bias[oc];
    #pragma unroll
    for (int m = 0; m < 2; ++m){
      #pragma unroll
      for (int r = 0; r < 4; ++r){
        const int ow = m*16 + (lane >> 4)*4 + r;
        if (ow >= 27) continue;
        float v = leakyf(acc[m][f][r] + bv);
        if (OUTM == 0){
          OutPad[(((size_t)n*29 + orow+1)*29 + ow+1)*OC + oc] = (_Float16)v;
        } else {
          OutNP[(((size_t)n*27 + orow)*27 + ow)*OC + oc] = (_Float16)v;
        }
      }
    }
  }
}

// ---------------- single-fp16 MFMA GEMM for MoE head ------------------------
template<int KTOT,int ACT,int OUTM>
__global__ __launch_bounds__(256) void gemmH_k(
    const _Float16* __restrict__ A, long strideA,
    const _Float16* __restrict__ W,
    const float* __restrict__ bias, int N,
    _Float16* __restrict__ OutH, float* __restrict__ OutF){
  const int e = blockIdx.z;
  A += (size_t)e * strideA;
  const int NF = N >> 4, KT = KTOT >> 5;
  W += (size_t)e * NF * KT * 512;
  const float* bs = bias + (size_t)e * N;
  const size_t ob = (size_t)e * 256 * N;

  const int tid = threadIdx.x, wid = tid >> 6, lane = tid & 63;
  const int mblk = blockIdx.x * 32;
  const int nf = blockIdx.y * 4 + wid;
  const int r0 = mblk + (lane & 15);
  const int kof = (lane >> 4) * 8;

  f32x4 acc0 = {0,0,0,0}, acc1 = {0,0,0,0};
  for (int t = 0; t < KT; ++t){
    const int k = t*32 + kof;
    f16x8 a0 = *(const f16x8*)(A + (size_t)r0*KTOT + k);
    f16x8 a1 = *(const f16x8*)(A + (size_t)(r0+16)*KTOT + k);
    const f16x8 b = *(const f16x8*)(W + ((size_t)t*NF + nf)*512 + lane*8);
    acc0 = __builtin_amdgcn_mfma_f32_16x16x32_f16(a0, b, acc0, 0,0,0);
    acc1 = __builtin_amdgcn_mfma_f32_16x16x32_f16(a1, b, acc1, 0,0,0);
  }
  const int n = nf*16 + (lane & 15);
  const float bv = bs[n];
  #pragma unroll
  for (int mi = 0; mi < 2; ++mi){
    f32x4 a = mi ? acc1 : acc0;
    #pragma unroll
    for (int r = 0; r < 4; ++r){
      const int m = mblk + mi*16 + (lane >> 4)*4 + r;
      float v = a[r] + bv;
      if (ACT == 1) v = leakyf(v);
      const size_t o = ob + (size_t)m*N + n;
      if (OUTM == 0) OutH[o] = (_Float16)v;
      else           OutF[o] = v;
    }
  }
}

// ------ fp16 NHWC 2x2 s1 maxpool: [B,56,56,16] -> [B,55,55,16] --------------
__global__ __launch_bounds__(256) void poolh_k(const _Float16* __restrict__ in,
                                               _Float16* __restrict__ out){
  int idx = blockIdx.x * 256 + threadIdx.x;
  if (idx >= BATCH * 55 * 55 * 2) return;
  int half = idx & 1; int p = idx >> 1;
  int ow = p % 55; int t = p / 55; int oh = t % 55; int n = t / 55;
  const _Float16* q = in + (((size_t)n*56 + oh)*56 + ow)*16 + half*8;
  f16x8 a = *(const f16x8*)q;
  f16x8 b = *(const f16x8*)(q + 16);
  f16x8 c = *(const f16x8*)(q + 56*16);
  f16x8 d = *(const f16x8*)(q + 57*16);
  f16x8 r;
  #pragma unroll
  for (int j = 0; j < 8; ++j){
    float m = fmaxf(fmaxf((float)a[j], (float)b[j]), fmaxf((float)c[j], (float)d[j]));
    r[j] = (_Float16)m;
  }
  *(f16x8*)(out + (size_t)p*16 + half*8) = r;
}

// ------- pool2: fp16 NHWC [B,28,28,32] -> padded NHWC fp16 [B,29,29,32] -----
__global__ __launch_bounds__(256) void pool2n_k(const _Float16* __restrict__ in,
    _Float16* __restrict__ o16){
  int idx = blockIdx.x*256 + threadIdx.x;
  if (idx >= BATCH*27*27*32) return;
  int ic = idx & 31; int p = idx >> 5;
  int ow = p % 27; int t = p / 27; int oh = t % 27; int n = t / 27;
  const _Float16* b = in + (((size_t)n*28 + oh)*28 + ow)*32 + ic;
  float v = fmaxf(fmaxf((float)b[0], (float)b[32]),
                  fmaxf((float)b[28*32], (float)b[29*32]));
  o16[(((size_t)n*29 + oh+1)*29 + ow+1)*32 + ic] = (_Float16)v;
}

// ---------------- gate from fused sums: [B,32] -> comb[B,3] -----------------
__global__ __launch_bounds__(256) void gate2_k(const float* __restrict__ gsum,
                                               const float* __restrict__ cw,
                                               const float* __restrict__ cb,
                                               float* __restrict__ comb){
  int n = blockIdx.x * 256 + threadIdx.x;
  if (n >= BATCH) return;
  float mch[32];
  #pragma unroll
  for (int c = 0; c < 32; ++c) mch[c] = gsum[n*32 + c] / 784.f;
  float lg[3];
  #pragma unroll
  for (int e = 0; e < 3; ++e){
    float a = cb[e];
    #pragma unroll
    for (int c = 0; c < 32; ++c) a += mch[c] * cw[e*32 + c];
    lg[e] = a;
  }
  float m = fmaxf(lg[0], fmaxf(lg[1], lg[2]));
  float ex[3], sum = 0.f;
  #pragma unroll
  for (int e = 0; e < 3; ++e){ ex[e] = expf(lg[e] - m); sum += ex[e]; }
  float pr[3];
  #pragma unroll
  for (int e = 0; e < 3; ++e) pr[e] = ex[e] / sum;
  int i1 = 0;
  if (pr[1] > pr[0]) i1 = 1;
  if (pr[2] > pr[i1]) i1 = 2;
  int i2 = -1;
  for (int e = 0; e < 3; ++e){
    if (e == i1) continue;
    if (i2 < 0 || pr[e] > pr[i2]) i2 = e;
  }
  float s12 = pr[i1] + pr[i2] + 1e-6f;
  float cmb[3] = {0.f, 0.f, 0.f};
  cmb[i1] = pr[i1] / s12;
  cmb[i2] = pr[i2] / s12;
  comb[n*3 + 0] = cmb[0];
  comb[n*3 + 1] = cmb[1];
  comb[n*3 + 2] = cmb[2];
}

// ------ channel-parallel fused maxpool2s1(27->26) + adaptive avg(26->3) -----
__global__ __launch_bounds__(256) void papool2_k(const _Float16* __restrict__ in,
                                                 float* __restrict__ flat){
  __shared__ float red[2][128][9];
  const int n = blockIdx.x;
  const int tid = threadIdx.x;
  const int h = tid >> 7, c = tid & 127;
  const _Float16* p = in + (size_t)n * 729 * 128 + c;

  float sum[9];
  #pragma unroll
  for (int j = 0; j < 9; ++j) sum[j] = 0.f;

  float prev[27], cur[27];
  const int r0 = h * 13;
  #pragma unroll
  for (int rr = 0; rr < 14; ++rr){
    const int r = r0 + rr;
    #pragma unroll
    for (int cc = 0; cc < 27; ++cc)
      cur[cc] = (float)p[(size_t)(r*27 + cc) * 128];
    if (rr > 0){
      const int pr = r - 1;
      const bool b0 = (pr < 9), b1 = (pr >= 8) && (pr < 18), b2 = (pr >= 17);
      #pragma unroll
      for (int cc = 0; cc < 26; ++cc){
        float v = fmaxf(fmaxf(prev[cc], prev[cc+1]), fmaxf(cur[cc], cur[cc+1]));
        if (b0){
          if (cc < 9)             sum[0] += v;
          if (cc >= 8 && cc < 18) sum[1] += v;
          if (cc >= 17)           sum[2] += v;
        }
        if (b1){
          if (cc < 9)             sum[3] += v;
          if (cc >= 8 && cc < 18) sum[4] += v;
          if (cc >= 17)           sum[5] += v;
        }
        if (b2){
          if (cc < 9)             sum[6] += v;
          if (cc >= 8 && cc < 18) sum[7] += v;
          if (cc >= 17)           sum[8] += v;
        }
      }
    }
    #pragma unroll
    for (int cc = 0; cc < 27; ++cc) prev[cc] = cur[cc];
  }

  #pragma unroll
  for (int j = 0; j < 9; ++j) red[h][c][j] = sum[j];
  __syncthreads();

  if (tid < 128){
    const float rcp[9] = {1.f/81, 1.f/90, 1.f/81, 1.f/90, 1.f/100, 1.f/90,
                          1.f/81, 1.f/90, 1.f/81};
    float* o = flat + (size_t)n * 1152 + tid * 9;
    #pragma unroll
    for (int j = 0; j < 9; ++j)
      o[j] = (red[0][tid][j] + red[1][tid][j]) * rcp[j];
  }
}

// ---------------- final gated combine ----------------
__global__ __launch_bounds__(256) void comb_k(const float* __restrict__ h3,
                                              const float* __restrict__ comb,
                                              float* __restrict__ out){
  int idx = blockIdx.x * 256 + threadIdx.x;
  if (idx >= BATCH * 512) return;
  int o = idx % 512, b = idx / 512;
  float s = 0.f;
  #pragma unroll
  for (int e = 0; e < 3; ++e)
    s += comb[b * 3 + e] * h3[((size_t)e * BATCH + b) * 512 + o];
  out[idx] = s;
}

// ============================================================================
extern "C" void kernel_launch(void* const* d_in, const int* in_sizes, int n_in,
                              void* d_out, int out_size, void* d_ws, size_t ws_size,
                              hipStream_t stream){
  const float* x    = (const float*)d_in[0];
  const float* tw1  = (const float*)d_in[1];  const float* tb1 = (const float*)d_in[2];
  const float* tw2  = (const float*)d_in[3];  const float* tb2 = (const float*)d_in[4];
  const float* tw3  = (const float*)d_in[5];  const float* tb3 = (const float*)d_in[6];
  const float* tw4  = (const float*)d_in[7];  const float* tb4 = (const float*)d_in[8];
  const float* sw1  = (const float*)d_in[9];  const float* sb1 = (const float*)d_in[10];
  const float* bn1g = (const float*)d_in[11]; const float* bn1b = (const float*)d_in[12];
  const float* bn1m = (const float*)d_in[13]; const float* bn1v = (const float*)d_in[14];
  const float* sw2  = (const float*)d_in[15]; const float* sb2 = (const float*)d_in[16];
  const float* bn2g = (const float*)d_in[17]; const float* bn2b = (const float*)d_in[18];
  const float* bn2m = (const float*)d_in[19]; const float* bn2v = (const float*)d_in[20];
  const float* cw   = (const float*)d_in[21]; const float* cb  = (const float*)d_in[22];
  const float* ew1  = (const float*)d_in[23]; const float* eb1 = (const float*)d_in[24];
  const float* ew2  = (const float*)d_in[25]; const float* eb2 = (const float*)d_in[26];
  const float* ew3  = (const float*)d_in[27]; const float* eb3 = (const float*)d_in[28];
  float* out = (float*)d_out;

  // ---- workspace layout (floats), ~157 MB ----
  float* ws = (float*)d_ws;
  size_t off = 0;
  float* comb   = ws + off; off += 768;
  float* flat   = ws + off; off += (size_t)BATCH * 1152;
  float* h3     = ws + off; off += (size_t)BATCH * 3 * 512;
  float* gsum   = ws + off; off += BATCH * 32;            // scout gate sums
  _Float16* wpk3 = (_Float16*)(ws + off); off += 9216;
  _Float16* wpk4 = (_Float16*)(ws + off); off += 36864;
  _Float16* wp2  = (_Float16*)(ws + off); off += 7680;
  _Float16* wps2 = (_Float16*)(ws + off); off += 3072;
  _Float16* wpf  = (_Float16*)(ws + off); off += 3072;
  off += 16;                                                      // guard pad
  float* bufA   = ws + off; off += 13778944;
  off += 16;                                                      // guard pad
  float* bufB   = ws + off; off += 23887872;
  off += 16;
  (void)ws_size; (void)in_sizes; (void)n_in; (void)out_size;

  // phase aliases (lifetimes disjoint, single-stream ordered)
  _Float16* s1h = (_Float16*)bufA;           // [B,56,56,16] fp16 NHWC
  _Float16* c1h = (_Float16*)bufB;           // [B,56,56,16] fp16 NHWC
  _Float16* p1h = (_Float16*)bufA;           // [B,55,55,16] fp16 NHWC
  _Float16* c2h = (_Float16*)bufB;           // [B,28,28,32] fp16 NHWC
  _Float16* P2 = (_Float16*)(bufB + 8000000);
  _Float16* C3 = (_Float16*)bufA;
  _Float16* c4h = (_Float16*)bufB;           // [B,27,27,128] fp16 NHWC

  // head-phase aliases in bufB (valid after papool2_k) — all fp16
  _Float16* hb = (_Float16*)bufB;
  size_t uo = 0;
  _Float16* ewp1 = hb + uo; uo += 3538944;
  _Float16* ewp2 = hb + uo; uo += 1572864;
  _Float16* ewp3 = hb + uo; uo += 786432;
  _Float16* f16a = hb + uo; uo += 294912;
  _Float16* h1   = hb + uo; uo += 786432;
  _Float16* h2   = hb + uo; uo += 393216;

  dim3 blk(256);

  // ---- weight prep + gate accumulator zero ----
  hipMemsetAsync(gsum, 0, BATCH * 32 * sizeof(float), stream);
  wpackM_k<32,64>  <<<dim3(72),  blk, 0, stream>>>(tw3, wpk3);
  wpackM_k<64,128> <<<dim3(288), blk, 0, stream>>>(tw4, wpk4);
  wpackS_k<32,5><<<dim3(60), blk, 0, stream>>>(tw2, wp2);
  wpackS_k<32,3><<<dim3(24), blk, 0, stream>>>(sw2, wps2);
  wpackF_k<<<dim3(24), blk, 0, stream>>>(sw1, tw1, wpf);

  // ---- fused scout1 + conv1 -> fp16 NHWC (single-barrier, SR staging) ----
  fusedM_k<<<dim3(BATCH*28), blk, 0, stream>>>(
      x, wpf, sb1, tb1, bn1g, bn1b, bn1m, bn1v, s1h, c1h);

  // ---- scout2 fused with gate spatial-sum (no tensor output) ----
  convS_k<32,3,1,56,56,1,false,true><<<dim3(BATCH*28), blk, 0, stream>>>(
      s1h, wps2, sb2, bn2g, bn2b, bn2m, bn2v, nullptr, nullptr, gsum);
  gate2_k<<<dim3(1), blk, 0, stream>>>(gsum, cw, cb, comb);

  // ---- pool1 (fp16 NHWC) -> conv2 (fp16 out) ----
  poolh_k<<<dim3((BATCH*55*55*2 + 255)/256), blk, 0, stream>>>(c1h, p1h);
  convS_k<32,5,2,55,55,0,true,false><<<dim3(BATCH*28), blk, 0, stream>>>(
      p1h, wp2, tb2, nullptr, nullptr, nullptr, nullptr, nullptr, c2h, nullptr);

  // ---- pool2 (fp16 in) -> padded NHWC fp16 ----
  hipMemsetAsync(P2, 0, (size_t)6889472 * 2, stream);
  pool2n_k<<<dim3((BATCH*27*27*32 + 255)/256), blk, 0, stream>>>(c2h, P2);

  // ---- conv3 (MFMA fp16) -> padded NHWC fp16 ----
  hipMemsetAsync(C3, 0, (size_t)13778944 * 2, stream);
  convM_k<32,64,0><<<dim3(BATCH*14), blk, 0, stream>>>(
      P2, wpk3, tb3, C3, nullptr);

  // ---- conv4 (MFMA fp16) -> fp16 NHWC [B,27,27,128] ----
  convM_k<64,128,1><<<dim3(BATCH*14), blk, 0, stream>>>(
      C3, wpk4, tb4, nullptr, c4h);

  papool2_k<<<dim3(BATCH), blk, 0, stream>>>(c4h, flat);

  // ---- MoE head: pack weights fp16 + convert A, then 3 fp16 MFMA GEMMs ----
  wpackGh_k<1152><<<dim3(4608,3), blk, 0, stream>>>(ew1, 1024, ewp1);
  wpackGh_k<1024><<<dim3(2048,3), blk, 0, stream>>>(ew2,  512, ewp2);
  wpackGh_k< 512><<<dim3(1024,3), blk, 0, stream>>>(ew3,  512, ewp3);
  acvt_k<<<dim3(1152), blk, 0, stream>>>(flat, f16a, BATCH*1152);

  gemmH_k<1152,1,0><<<dim3(8,16,3), blk, 0, stream>>>(
      f16a, 0L, ewp1, eb1, 1024, h1, nullptr);
  gemmH_k<1024,1,0><<<dim3(8,8,3), blk, 0, stream>>>(
      h1, 256L*1024, ewp2, eb2, 512, h2, nullptr);
  gemmH_k< 512,0,1><<<dim3(8,8,3), blk, 0, stream>>>(
      h2, 256L*512, ewp3, eb3, 512, nullptr, h3);

  comb_k<<<dim3(512), blk, 0, stream>>>(h3, comb, out);
}

// Round 20
// 275.823 us; speedup vs baseline: 1.1009x; 1.1009x over previous
//
#include <hip/hip_runtime.h>

#define DEV static __device__ __forceinline__

constexpr int BATCH = 256;

DEV float leakyf(float x){ return x > 0.f ? x : 0.2f * x; }

typedef _Float16 f16x8 __attribute__((ext_vector_type(8)));
typedef float f32x4 __attribute__((ext_vector_type(4)));

DEV f16x8 max8(f16x8 a, f16x8 b){
  f16x8 r;
  #pragma unroll
  for (int j = 0; j < 8; ++j) r[j] = a[j] > b[j] ? a[j] : b[j];
  return r;
}

// ------- pack OIHW conv weights into MFMA B-fragment order, single fp16 -----
template<int IC,int OC>
__global__ __launch_bounds__(256) void wpackM_k(const float* __restrict__ w,
    _Float16* __restrict__ wp){
  constexpr int S = IC/32, F = OC/16;
  int i = blockIdx.x*256 + threadIdx.x;
  if (i >= 9*S*F*512) return;
  int j = i & 7, L = (i >> 3) & 63, rest = i >> 9;
  int f = rest % F; int q2 = rest / F; int s = q2 % S; int t = q2 / S;
  int oc = f*16 + (L & 15), ic = s*32 + (L >> 4)*8 + j;
  wp[i] = (_Float16)w[((size_t)oc*IC + ic)*9 + t];
}

// ------- pack strided-conv weights (IC=16), single fp16 ---------------------
template<int OC,int K>
__global__ __launch_bounds__(256) void wpackS_k(const float* __restrict__ w,
    _Float16* __restrict__ wp){
  constexpr int F = OC/16, KWP = (K+1)/2;
  int i = blockIdx.x*256 + threadIdx.x;
  if (i >= K*KWP*F*512) return;
  int j = i & 7, L = (i >> 3) & 63, rest = i >> 9;
  int f = rest % F, s = rest / F;
  int kh = s / KWP, kwp = s % KWP;
  int k = (L >> 4)*8 + j;
  int kw = 2*kwp + (k >> 4), ic = k & 15;
  int oc = f*16 + (L & 15);
  float v = (kw < K) ? w[((size_t)(oc*16 + ic)*K + kh)*K + kw] : 0.f;
  wp[i] = (_Float16)v;
}

// ------- pack scout1(k7) + conv1(k3) weights, space-to-depth, single fp16 ---
__global__ __launch_bounds__(256) void wpackF_k(const float* __restrict__ sw1,
    const float* __restrict__ tw1, _Float16* __restrict__ wp){
  int i = blockIdx.x*256 + threadIdx.x;
  if (i >= 6*2*512) return;
  int j = i & 7, L = (i >> 3) & 63, rest = i >> 9;
  int nf = rest & 1, s = rest >> 1;
  int k = s*32 + (L >> 4)*8 + j;
  int oc = L & 15;
  int t = k / 48, c = k % 48;
  int dr = (t >> 1) - 1, dc = (t & 1) - 1;
  int ic = c >> 4, pr = (c >> 2) & 3, pc = c & 3;
  float v = 0.f;
  if (nf == 0){
    int kh = 4*dr + pr + 3, kw = 4*dc + pc + 3;
    if (kh >= 0 && kh < 7 && kw >= 0 && kw < 7) v = sw1[((oc*3 + ic)*7 + kh)*7 + kw];
  } else {
    int kh = 4*dr + pr + 1, kw = 4*dc + pc + 1;
    if (kh >= 0 && kh < 3 && kw >= 0 && kw < 3) v = tw1[((oc*3 + ic)*3 + kh)*3 + kw];
  }
  wp[i] = (_Float16)v;
}

// ------- pack expert GEMM weights W[e][N][K] into frag order, single fp16 ---
template<int KTOT>
__global__ __launch_bounds__(256) void wpackGh_k(const float* __restrict__ w, int N,
    _Float16* __restrict__ wp){
  const int NF = N >> 4, KT = KTOT >> 5;
  const int total = NF * KT * 512;
  const int e = blockIdx.y;
  w  += (size_t)e * N * KTOT;
  wp += (size_t)e * total;
  int i = blockIdx.x*256 + threadIdx.x;
  if (i >= total) return;
  int j = i & 7, L = (i >> 3) & 63, rest = i >> 9;
  int nf = rest % NF, t = rest / NF;
  int n = nf*16 + (L & 15), k = t*32 + (L >> 4)*8 + j;
  wp[i] = (_Float16)w[(size_t)n*KTOT + k];
}

// ------- convert fp32 array to fp16 ----------------------------------------
__global__ __launch_bounds__(256) void acvt_k(const float* __restrict__ in,
    _Float16* __restrict__ o16, int nelem){
  int i = blockIdx.x*256 + threadIdx.x;
  if (i >= nelem) return;
  o16[i] = (_Float16)in[i];
}

// ---------- fused scout1+conv1, space-to-depth MFMA fp16, SINGLE barrier ----
__global__ __launch_bounds__(256) void fusedM_k(
    const float* __restrict__ x,
    const _Float16* __restrict__ W,
    const float* __restrict__ sb, const float* __restrict__ cb_,
    const float* __restrict__ g, const float* __restrict__ bt,
    const float* __restrict__ mn, const float* __restrict__ vr,
    _Float16* __restrict__ s1out, _Float16* __restrict__ c1out){
  __shared__ __align__(16) _Float16 Ah[3*58*64];
  const int tid = threadIdx.x;
  const int n = blockIdx.x / 28, oh0 = (blockIdx.x % 28) * 2;

  if (tid < 48){
    int rr = tid >> 4, side = (tid >> 3) & 1, q = tid & 7;
    int col = side ? 57 : 0;
    *(int4*)((char*)Ah + (((rr*58 + col) << 7) + q*16)) = (int4){0,0,0,0};
  }

  {
    const int m = tid & 63;
    const bool mok = (m < 56);
    const int cc = m + 1;
    int rc0 = tid >> 6;
    int ic   = (rc0 == 3) ? 0 : rc0;
    int ridx = (rc0 == 3) ? 1 : 0;
    #pragma unroll
    for (int j = 0; j < 9; ++j){
      const int ih = 4*oh0 - 4 + ridx;
      if (mok){
        float4 v = {0.f,0.f,0.f,0.f};
        if (ih >= 0)
          v = *(const float4*)(x + ((size_t)(n*3 + ic)*224 + ih)*224 + 4*m);
        const int rr = ridx >> 2, pr = ridx & 3;
        int boff = (((rr*58 + cc) << 7) + ic*32 + pr*8) ^ ((cc & 7) << 4);
        _Float16 h4[4] = {(_Float16)v.x, (_Float16)v.y, (_Float16)v.z, (_Float16)v.w};
        *(unsigned long long*)((char*)Ah + boff) = *(unsigned long long*)h4;
      }
      ic += 1; ridx += 1;
      if (ic >= 3){ ic -= 3; ridx += 1; }
    }
  }
  __syncthreads();

  const int wid = tid >> 6, lane = tid & 63;
  const int kg8 = (lane >> 4) * 8;
  f32x4 acc[2][2];
  #pragma unroll
  for (int mi = 0; mi < 2; ++mi)
    #pragma unroll
    for (int nf = 0; nf < 2; ++nf) acc[mi][nf] = (f32x4){0.f,0.f,0.f,0.f};

  #pragma unroll
  for (int s = 0; s < 6; ++s){
    const int kk = s*32 + kg8;
    const int t = kk / 48, c0 = kk - t*48;
    const int ra = t >> 1, ca = t & 1;
    f16x8 ah[2];
    #pragma unroll
    for (int mi = 0; mi < 2; ++mi){
      const int m = 2*wid + mi;
      const int rowsel = m >> 2;
      const int ow = (m & 3)*16 + (lane & 15);
      const int owc = ow > 55 ? 55 : ow;
      const int col = owc + ca;
      const int bidx = ((((rowsel + ra)*58 + col) << 7) + c0*2) ^ ((col & 7) << 4);
      ah[mi] = *(const f16x8*)((const char*)Ah + bidx);
    }
    #pragma unroll
    for (int nf = 0; nf < 2; ++nf){
      const f16x8 bw = *(const f16x8*)(W + (s*2 + nf)*512 + lane*8);
      #pragma unroll
      for (int mi = 0; mi < 2; ++mi)
        acc[mi][nf] = __builtin_amdgcn_mfma_f32_16x16x32_f16(ah[mi], bw, acc[mi][nf], 0,0,0);
    }
  }

  const int oc = lane & 15;
  const float sbv = sb[oc];
  const float scv = g[oc] * __frsqrt_rn(vr[oc] + 1e-5f);
  const float mnv = mn[oc], btv = bt[oc], cbv = cb_[oc];
  #pragma unroll
  for (int mi = 0; mi < 2; ++mi){
    const int m = 2*wid + mi;
    const int row = oh0 + (m >> 2);
    const int owb = (m & 3)*16 + (lane >> 4)*4;
    #pragma unroll
    for (int r = 0; r < 4; ++r){
      const int ow = owb + r;
      if (ow >= 56) continue;
      float vs = acc[mi][0][r] + sbv;
      vs = fmaxf((vs - mnv)*scv + btv, 0.f);
      const size_t o = (((size_t)n*56 + row)*56 + ow)*16 + oc;
      s1out[o] = (_Float16)vs;
      c1out[o] = (_Float16)leakyf(acc[mi][1][r] + cbv);
    }
  }
}

// ---------------- strided (S=2) MFMA conv, fp16 NHWC input ------------------
// POOLIN: input is pre-pool [B,IH+1,IW+1,16]; staging fuses 2x2 s1 maxpool.
// GATE: BN+relu then spatial-sum -> atomicAdd gsum[n*32+oc] (no tensor out).
template<int OC,int K,int P,int IH,int IW,int ACT,bool OUT16,bool GATE,bool POOLIN>
__global__ __launch_bounds__(256) void convS_k(
    const _Float16* __restrict__ in,
    const _Float16* __restrict__ W,
    const float* __restrict__ bias,
    const float* __restrict__ bng, const float* __restrict__ bnb,
    const float* __restrict__ bnm, const float* __restrict__ bnv,
    float* __restrict__ outF, _Float16* __restrict__ outH,
    float* __restrict__ gsum){
  constexpr int F = OC/16, KWP = (K+1)/2;
  constexpr int RW = POOLIN ? (IW+1) : IW;   // raw row pitch (cols)
  __shared__ __align__(16) _Float16 A[K*60*16];
  __shared__ float gred[32];

  const int tid = threadIdx.x;
  const int n = blockIdx.x / 28, oh = blockIdx.x % 28;

  if (GATE && tid < 32) gred[tid] = 0.f;

  for (int i = tid; i < K*60*2; i += 256){
    int half = i & 1; int p = i >> 1;
    int c = p % 60; int r = p / 60;
    int ih = 2*oh - P + r, iw = c - P;
    int4 v = {0,0,0,0};
    if (ih >= 0 && ih < IH && iw >= 0 && iw < IW){
      const _Float16* q = in + (((size_t)n*(POOLIN ? IH+1 : IH) + ih)*RW + iw)*16 + half*8;
      if (POOLIN){
        f16x8 a = *(const f16x8*)q;
        f16x8 b = *(const f16x8*)(q + 16);
        f16x8 cc = *(const f16x8*)(q + RW*16);
        f16x8 d = *(const f16x8*)(q + RW*16 + 16);
        f16x8 mx = max8(max8(a, b), max8(cc, d));
        v = *(int4*)&mx;
      } else {
        v = *(const int4*)q;
      }
    }
    int byte = ((r*60 + c)*32 + half*16) ^ (((c>>1)&7) << 4);
    *(int4*)((char*)A + byte) = v;
  }
  __syncthreads();

  const int wid = tid >> 6, lane = tid & 63;
  const int fsel = wid & 1, mb = wid >> 1;
  const int ow_l = min(mb*16 + (lane & 15), 27);
  const int ic0b = ((lane >> 4) & 1) * 16;
  const int kwo  = (lane >> 4) >> 1;

  f32x4 acc = {0.f,0.f,0.f,0.f};
  #pragma unroll
  for (int kh = 0; kh < K; ++kh){
    #pragma unroll
    for (int kwp = 0; kwp < KWP; ++kwp){
      const int kw = 2*kwp + kwo;
      const int c = 2*ow_l + kw;
      int byte = ((kh*60 + c)*32 + ic0b) ^ (((c>>1)&7) << 4);
      f16x8 a = *(const f16x8*)((const char*)A + byte);
      const int s = kh*KWP + kwp;
      const f16x8 b = *(const f16x8*)(W + (s*F + fsel)*512 + lane*8);
      acc = __builtin_amdgcn_mfma_f32_16x16x32_f16(a, b, acc, 0,0,0);
    }
  }

  const int oc = fsel*16 + (lane & 15);
  float bv = bias[oc], sc = 1.f, mm = 0.f, bb = 0.f;
  if (ACT == 1){
    sc = bng[oc] * __frsqrt_rn(bnv[oc] + 1e-5f);
    mm = bnm[oc]; bb = bnb[oc];
  }
  float lsum = 0.f;
  #pragma unroll
  for (int r = 0; r < 4; ++r){
    const int ow = mb*16 + (lane >> 4)*4 + r;
    if (ow >= 28) continue;
    float v = acc[r] + bv;
    if (ACT == 1) v = fmaxf((v - mm)*sc + bb, 0.f);
    else          v = leakyf(v);
    if (GATE){
      lsum += v;
    } else {
      const size_t o = (((size_t)n*28 + oh)*28 + ow)*OC + oc;
      if (OUT16) outH[o] = (_Float16)v;
      else       outF[o] = v;
    }
  }
  if (GATE){
    atomicAdd(&gred[oc], lsum);
    __syncthreads();
    if (tid < 32) atomicAdd(&gsum[n*32 + tid], gred[tid]);
  }
}

// ---------------- MFMA fp16 3x3 s1 p1 conv on 27x27, unpadded NHWC ----------
// POOLIN: input is pre-pool [B,28,28,IC]; staging fuses 2x2 s1 maxpool.
// else: input unpadded [B,27,27,IC]. Output: unpadded fp16 [B,27,27,OC].
template<int IC,int OC,bool POOLIN>
__global__ __launch_bounds__(256) void convM_k(
    const _Float16* __restrict__ Ag,
    const _Float16* __restrict__ W,
    const float* __restrict__ bias,
    _Float16* __restrict__ Out)
{
  constexpr int S = IC/32, FTOT = OC/16, FW = FTOT/2;
  constexpr int ICB = IC*2, ICG = ICB/16;
  __shared__ __align__(16) char A[4*34*ICB];

  const int tid = threadIdx.x;
  const int bx = blockIdx.x;
  const int n = bx / 14, pr = bx % 14;
  const int oh0 = pr * 2;

  for (int g = tid; g < 4*34*ICG; g += 256){
    int r = g / (34*ICG);
    int rem = g - r*(34*ICG);
    int c = rem / ICG, q = rem - c*ICG;
    int ir = oh0 + r - 1, icol = c - 1;
    int4 v = {0,0,0,0};
    if (ir >= 0 && ir < 27 && icol >= 0 && icol < 27){
      if (POOLIN){
        const _Float16* p0 = Ag + (((size_t)n*28 + ir)*28 + icol)*IC + q*8;
        f16x8 a = *(const f16x8*)p0;
        f16x8 b = *(const f16x8*)(p0 + IC);
        f16x8 cc = *(const f16x8*)(p0 + 28*IC);
        f16x8 d = *(const f16x8*)(p0 + 28*IC + IC);
        f16x8 mx = max8(max8(a, b), max8(cc, d));
        v = *(int4*)&mx;
      } else {
        v = *(const int4*)(Ag + (((size_t)n*27 + ir)*27 + icol)*IC + q*8);
      }
    }
    int off = (r*34 + c)*ICB + q*16;
    int swz = off ^ ((c & 7) << 4);
    *(int4*)(A + swz) = v;
  }
  __syncthreads();

  const int wid = tid >> 6, lane = tid & 63;
  const int rsel = wid & 1, ocq = wid >> 1;
  const int c0 = lane & 15, kg = (lane >> 4) * 16;
  const int colb0 = c0*ICB + kg, colb1 = (16 + c0)*ICB + kg;
  int msk[3];
  #pragma unroll
  for (int kw = 0; kw < 3; ++kw) msk[kw] = ((c0 + kw) & 7) << 4;

  f32x4 acc[2][FW];
  #pragma unroll
  for (int m = 0; m < 2; ++m)
    #pragma unroll
    for (int f = 0; f < FW; ++f) acc[m][f] = (f32x4){0.f,0.f,0.f,0.f};

  #pragma unroll
  for (int kh = 0; kh < 3; ++kh){
    #pragma unroll
    for (int kw = 0; kw < 3; ++kw){
      #pragma unroll
      for (int s = 0; s < S; ++s){
        const int fr0 = (((kh*3 + kw)*S + s)*FTOT + ocq*FW) * 512 + lane*8;
        f16x8 b[FW];
        #pragma unroll
        for (int f = 0; f < FW; ++f)
          b[f] = *(const f16x8*)(W + fr0 + f*512);
        const int base = ((rsel + kh)*34 + kw)*ICB + s*64;
        const int o0 = (base + colb0) ^ msk[kw];
        const int o1 = (base + colb1) ^ msk[kw];
        f16x8 a0 = *(const f16x8*)(A + o0);
        f16x8 a1 = *(const f16x8*)(A + o1);
        #pragma unroll
        for (int f = 0; f < FW; ++f){
          acc[0][f] = __builtin_amdgcn_mfma_f32_16x16x32_f16(a0, b[f], acc[0][f], 0,0,0);
          acc[1][f] = __builtin_amdgcn_mfma_f32_16x16x32_f16(a1, b[f], acc[1][f], 0,0,0);
        }
      }
    }
  }

  const int orow = oh0 + rsel;
  if (orow >= 27) return;
  #pragma unroll
  for (int f = 0; f < FW; ++f){
    const int oc = (ocq*FW + f)*16 + c0;
    const float bv = bias[oc];
    #pragma unroll
    for (int m = 0; m < 2; ++m){
      #pragma unroll
      for (int r = 0; r < 4; ++r){
        const int ow = m*16 + (lane >> 4)*4 + r;
        if (ow >= 27) continue;
        float v = leakyf(acc[m][f][r] + bv);
        Out[(((size_t)n*27 + orow)*27 + ow)*OC + oc] = (_Float16)v;
      }
    }
  }
}

// ---------------- single-fp16 MFMA GEMM for MoE head ------------------------
template<int KTOT,int ACT,int OUTM>
__global__ __launch_bounds__(256) void gemmH_k(
    const _Float16* __restrict__ A, long strideA,
    const _Float16* __restrict__ W,
    const float* __restrict__ bias, int N,
    _Float16* __restrict__ OutH, float* __restrict__ OutF){
  const int e = blockIdx.z;
  A += (size_t)e * strideA;
  const int NF = N >> 4, KT = KTOT >> 5;
  W += (size_t)e * NF * KT * 512;
  const float* bs = bias + (size_t)e * N;
  const size_t ob = (size_t)e * 256 * N;

  const int tid = threadIdx.x, wid = tid >> 6, lane = tid & 63;
  const int mblk = blockIdx.x * 32;
  const int nf = blockIdx.y * 4 + wid;
  const int r0 = mblk + (lane & 15);
  const int kof = (lane >> 4) * 8;

  f32x4 acc0 = {0,0,0,0}, acc1 = {0,0,0,0};
  for (int t = 0; t < KT; ++t){
    const int k = t*32 + kof;
    f16x8 a0 = *(const f16x8*)(A + (size_t)r0*KTOT + k);
    f16x8 a1 = *(const f16x8*)(A + (size_t)(r0+16)*KTOT + k);
    const f16x8 b = *(const f16x8*)(W + ((size_t)t*NF + nf)*512 + lane*8);
    acc0 = __builtin_amdgcn_mfma_f32_16x16x32_f16(a0, b, acc0, 0,0,0);
    acc1 = __builtin_amdgcn_mfma_f32_16x16x32_f16(a1, b, acc1, 0,0,0);
  }
  const int n = nf*16 + (lane & 15);
  const float bv = bs[n];
  #pragma unroll
  for (int mi = 0; mi < 2; ++mi){
    f32x4 a = mi ? acc1 : acc0;
    #pragma unroll
    for (int r = 0; r < 4; ++r){
      const int m = mblk + mi*16 + (lane >> 4)*4 + r;
      float v = a[r] + bv;
      if (ACT == 1) v = leakyf(v);
      const size_t o = ob + (size_t)m*N + n;
      if (OUTM == 0) OutH[o] = (_Float16)v;
      else           OutF[o] = v;
    }
  }
}

// ---------------- gate from fused sums: [B,32] -> comb[B,3] -----------------
__global__ __launch_bounds__(256) void gate2_k(const float* __restrict__ gsum,
                                               const float* __restrict__ cw,
                                               const float* __restrict__ cb,
                                               float* __restrict__ comb){
  int n = blockIdx.x * 256 + threadIdx.x;
  if (n >= BATCH) return;
  float mch[32];
  #pragma unroll
  for (int c = 0; c < 32; ++c) mch[c] = gsum[n*32 + c] / 784.f;
  float lg[3];
  #pragma unroll
  for (int e = 0; e < 3; ++e){
    float a = cb[e];
    #pragma unroll
    for (int c = 0; c < 32; ++c) a += mch[c] * cw[e*32 + c];
    lg[e] = a;
  }
  float m = fmaxf(lg[0], fmaxf(lg[1], lg[2]));
  float ex[3], sum = 0.f;
  #pragma unroll
  for (int e = 0; e < 3; ++e){ ex[e] = expf(lg[e] - m); sum += ex[e]; }
  float pr[3];
  #pragma unroll
  for (int e = 0; e < 3; ++e) pr[e] = ex[e] / sum;
  int i1 = 0;
  if (pr[1] > pr[0]) i1 = 1;
  if (pr[2] > pr[i1]) i1 = 2;
  int i2 = -1;
  for (int e = 0; e < 3; ++e){
    if (e == i1) continue;
    if (i2 < 0 || pr[e] > pr[i2]) i2 = e;
  }
  float s12 = pr[i1] + pr[i2] + 1e-6f;
  float cmb[3] = {0.f, 0.f, 0.f};
  cmb[i1] = pr[i1] / s12;
  cmb[i2] = pr[i2] / s12;
  comb[n*3 + 0] = cmb[0];
  comb[n*3 + 1] = cmb[1];
  comb[n*3 + 2] = cmb[2];
}

// ------ channel-parallel fused maxpool2s1(27->26) + adaptive avg(26->3) -----
__global__ __launch_bounds__(256) void papool2_k(const _Float16* __restrict__ in,
                                                 float* __restrict__ flat){
  __shared__ float red[2][128][9];
  const int n = blockIdx.x;
  const int tid = threadIdx.x;
  const int h = tid >> 7, c = tid & 127;
  const _Float16* p = in + (size_t)n * 729 * 128 + c;

  float sum[9];
  #pragma unroll
  for (int j = 0; j < 9; ++j) sum[j] = 0.f;

  float prev[27], cur[27];
  const int r0 = h * 13;
  #pragma unroll
  for (int rr = 0; rr < 14; ++rr){
    const int r = r0 + rr;
    #pragma unroll
    for (int cc = 0; cc < 27; ++cc)
      cur[cc] = (float)p[(size_t)(r*27 + cc) * 128];
    if (rr > 0){
      const int pr = r - 1;
      const bool b0 = (pr < 9), b1 = (pr >= 8) && (pr < 18), b2 = (pr >= 17);
      #pragma unroll
      for (int cc = 0; cc < 26; ++cc){
        float v = fmaxf(fmaxf(prev[cc], prev[cc+1]), fmaxf(cur[cc], cur[cc+1]));
        if (b0){
          if (cc < 9)             sum[0] += v;
          if (cc >= 8 && cc < 18) sum[1] += v;
          if (cc >= 17)           sum[2] += v;
        }
        if (b1){
          if (cc < 9)             sum[3] += v;
          if (cc >= 8 && cc < 18) sum[4] += v;
          if (cc >= 17)           sum[5] += v;
        }
        if (b2){
          if (cc < 9)             sum[6] += v;
          if (cc >= 8 && cc < 18) sum[7] += v;
          if (cc >= 17)           sum[8] += v;
        }
      }
    }
    #pragma unroll
    for (int cc = 0; cc < 27; ++cc) prev[cc] = cur[cc];
  }

  #pragma unroll
  for (int j = 0; j < 9; ++j) red[h][c][j] = sum[j];
  __syncthreads();

  if (tid < 128){
    const float rcp[9] = {1.f/81, 1.f/90, 1.f/81, 1.f/90, 1.f/100, 1.f/90,
                          1.f/81, 1.f/90, 1.f/81};
    float* o = flat + (size_t)n * 1152 + tid * 9;
    #pragma unroll
    for (int j = 0; j < 9; ++j)
      o[j] = (red[0][tid][j] + red[1][tid][j]) * rcp[j];
  }
}

// ---------------- final gated combine ----------------
__global__ __launch_bounds__(256) void comb_k(const float* __restrict__ h3,
                                              const float* __restrict__ comb,
                                              float* __restrict__ out){
  int idx = blockIdx.x * 256 + threadIdx.x;
  if (idx >= BATCH * 512) return;
  int o = idx % 512, b = idx / 512;
  float s = 0.f;
  #pragma unroll
  for (int e = 0; e < 3; ++e)
    s += comb[b * 3 + e] * h3[((size_t)e * BATCH + b) * 512 + o];
  out[idx] = s;
}

// ============================================================================
extern "C" void kernel_launch(void* const* d_in, const int* in_sizes, int n_in,
                              void* d_out, int out_size, void* d_ws, size_t ws_size,
                              hipStream_t stream){
  const float* x    = (const float*)d_in[0];
  const float* tw1  = (const float*)d_in[1];  const float* tb1 = (const float*)d_in[2];
  const float* tw2  = (const float*)d_in[3];  const float* tb2 = (const float*)d_in[4];
  const float* tw3  = (const float*)d_in[5];  const float* tb3 = (const float*)d_in[6];
  const float* tw4  = (const float*)d_in[7];  const float* tb4 = (const float*)d_in[8];
  const float* sw1  = (const float*)d_in[9];  const float* sb1 = (const float*)d_in[10];
  const float* bn1g = (const float*)d_in[11]; const float* bn1b = (const float*)d_in[12];
  const float* bn1m = (const float*)d_in[13]; const float* bn1v = (const float*)d_in[14];
  const float* sw2  = (const float*)d_in[15]; const float* sb2 = (const float*)d_in[16];
  const float* bn2g = (const float*)d_in[17]; const float* bn2b = (const float*)d_in[18];
  const float* bn2m = (const float*)d_in[19]; const float* bn2v = (const float*)d_in[20];
  const float* cw   = (const float*)d_in[21]; const float* cb  = (const float*)d_in[22];
  const float* ew1  = (const float*)d_in[23]; const float* eb1 = (const float*)d_in[24];
  const float* ew2  = (const float*)d_in[25]; const float* eb2 = (const float*)d_in[26];
  const float* ew3  = (const float*)d_in[27]; const float* eb3 = (const float*)d_in[28];
  float* out = (float*)d_out;

  // ---- workspace layout (floats), ~157 MB ----
  float* ws = (float*)d_ws;
  size_t off = 0;
  float* comb   = ws + off; off += 768;
  float* flat   = ws + off; off += (size_t)BATCH * 1152;
  float* h3     = ws + off; off += (size_t)BATCH * 3 * 512;
  float* gsum   = ws + off; off += BATCH * 32;
  _Float16* wpk3 = (_Float16*)(ws + off); off += 9216;
  _Float16* wpk4 = (_Float16*)(ws + off); off += 36864;
  _Float16* wp2  = (_Float16*)(ws + off); off += 7680;
  _Float16* wps2 = (_Float16*)(ws + off); off += 3072;
  _Float16* wpf  = (_Float16*)(ws + off); off += 3072;
  off += 16;                                                      // guard pad
  float* bufA   = ws + off; off += 13778944;
  off += 16;                                                      // guard pad
  float* bufB   = ws + off; off += 23887872;
  off += 16;
  (void)ws_size; (void)in_sizes; (void)n_in; (void)out_size;

  // phase aliases (lifetimes disjoint, single-stream ordered)
  _Float16* s1h = (_Float16*)bufA;             // [B,56,56,16] fp16 NHWC
  _Float16* c1h = (_Float16*)bufB;             // [B,56,56,16] fp16 NHWC (25.7MB)
  _Float16* c2h = (_Float16*)(bufB + 14000000);// [B,28,28,32] fp16 NHWC (12.8MB)
  _Float16* C3u = (_Float16*)bufA;             // [B,27,27,64] fp16 unpadded (23.9MB)
  _Float16* c4h = (_Float16*)bufB;             // [B,27,27,128] fp16 NHWC (23.9MB)

  // head-phase aliases in bufB (valid after papool2_k) — all fp16
  _Float16* hb = (_Float16*)bufB;
  size_t uo = 0;
  _Float16* ewp1 = hb + uo; uo += 3538944;
  _Float16* ewp2 = hb + uo; uo += 1572864;
  _Float16* ewp3 = hb + uo; uo += 786432;
  _Float16* f16a = hb + uo; uo += 294912;
  _Float16* h1   = hb + uo; uo += 786432;
  _Float16* h2   = hb + uo; uo += 393216;

  dim3 blk(256);

  // ---- weight prep + gate accumulator zero ----
  hipMemsetAsync(gsum, 0, BATCH * 32 * sizeof(float), stream);
  wpackM_k<32,64>  <<<dim3(72),  blk, 0, stream>>>(tw3, wpk3);
  wpackM_k<64,128> <<<dim3(288), blk, 0, stream>>>(tw4, wpk4);
  wpackS_k<32,5><<<dim3(60), blk, 0, stream>>>(tw2, wp2);
  wpackS_k<32,3><<<dim3(24), blk, 0, stream>>>(sw2, wps2);
  wpackF_k<<<dim3(24), blk, 0, stream>>>(sw1, tw1, wpf);

  // ---- fused scout1 + conv1 -> fp16 NHWC ----
  fusedM_k<<<dim3(BATCH*28), blk, 0, stream>>>(
      x, wpf, sb1, tb1, bn1g, bn1b, bn1m, bn1v, s1h, c1h);

  // ---- scout2 fused with gate spatial-sum (no tensor output) ----
  convS_k<32,3,1,56,56,1,false,true,false><<<dim3(BATCH*28), blk, 0, stream>>>(
      s1h, wps2, sb2, bn2g, bn2b, bn2m, bn2v, nullptr, nullptr, gsum);
  gate2_k<<<dim3(1), blk, 0, stream>>>(gsum, cw, cb, comb);

  // ---- conv2 with fused pool1 (stages 2x2 max from c1h) -> fp16 c2h ----
  convS_k<32,5,2,55,55,0,true,false,true><<<dim3(BATCH*28), blk, 0, stream>>>(
      c1h, wp2, tb2, nullptr, nullptr, nullptr, nullptr, nullptr, c2h, nullptr);

  // ---- conv3 with fused pool2 (stages 2x2 max from c2h) -> unpadded C3u ----
  convM_k<32,64,true><<<dim3(BATCH*14), blk, 0, stream>>>(
      c2h, wpk3, tb3, C3u);

  // ---- conv4 (unpadded input, predicated staging) -> fp16 c4h ----
  convM_k<64,128,false><<<dim3(BATCH*14), blk, 0, stream>>>(
      C3u, wpk4, tb4, c4h);

  papool2_k<<<dim3(BATCH), blk, 0, stream>>>(c4h, flat);

  // ---- MoE head: pack weights fp16 + convert A, then 3 fp16 MFMA GEMMs ----
  wpackGh_k<1152><<<dim3(4608,3), blk, 0, stream>>>(ew1, 1024, ewp1);
  wpackGh_k<1024><<<dim3(2048,3), blk, 0, stream>>>(ew2,  512, ewp2);
  wpackGh_k< 512><<<dim3(1024,3), blk, 0, stream>>>(ew3,  512, ewp3);
  acvt_k<<<dim3(1152), blk, 0, stream>>>(flat, f16a, BATCH*1152);

  gemmH_k<1152,1,0><<<dim3(8,16,3), blk, 0, stream>>>(
      f16a, 0L, ewp1, eb1, 1024, h1, nullptr);
  gemmH_k<1024,1,0><<<dim3(8,8,3), blk, 0, stream>>>(
      h1, 256L*1024, ewp2, eb2, 512, h2, nullptr);
  gemmH_k< 512,0,1><<<dim3(8,8,3), blk, 0, stream>>>(
      h2, 256L*512, ewp3, eb3, 512, nullptr, h3);

  comb_k<<<dim3(512), blk, 0, stream>>>(h3, comb, out);
}

// Round 21
// 265.920 us; speedup vs baseline: 1.1419x; 1.0372x over previous
//
#include <hip/hip_runtime.h>

#define DEV static __device__ __forceinline__

constexpr int BATCH = 256;

DEV float leakyf(float x){ return x > 0.f ? x : 0.2f * x; }

typedef _Float16 f16x8 __attribute__((ext_vector_type(8)));
typedef float f32x4 __attribute__((ext_vector_type(4)));

DEV f16x8 max8(f16x8 a, f16x8 b){
  f16x8 r;
  #pragma unroll
  for (int j = 0; j < 8; ++j) r[j] = a[j] > b[j] ? a[j] : b[j];
  return r;
}

// ---------------- weight-pack bodies (same math as before) ------------------
template<int IC,int OC>
DEV void wpackM_body(int i, const float* __restrict__ w, _Float16* __restrict__ wp){
  constexpr int F = OC/16;
  int j = i & 7, L = (i >> 3) & 63, rest = i >> 9;
  int f = rest % F; int q2 = rest / F; int s = q2 % (IC/32); int t = q2 / (IC/32);
  int oc = f*16 + (L & 15), ic = s*32 + (L >> 4)*8 + j;
  wp[i] = (_Float16)w[((size_t)oc*IC + ic)*9 + t];
}

template<int OC,int K>
DEV void wpackS_body(int i, const float* __restrict__ w, _Float16* __restrict__ wp){
  constexpr int F = OC/16, KWP = (K+1)/2;
  int j = i & 7, L = (i >> 3) & 63, rest = i >> 9;
  int f = rest % F, s = rest / F;
  int kh = s / KWP, kwp = s % KWP;
  int k = (L >> 4)*8 + j;
  int kw = 2*kwp + (k >> 4), ic = k & 15;
  int oc = f*16 + (L & 15);
  float v = (kw < K) ? w[((size_t)(oc*16 + ic)*K + kh)*K + kw] : 0.f;
  wp[i] = (_Float16)v;
}

DEV void wpackF_body(int i, const float* __restrict__ sw1,
                     const float* __restrict__ tw1, _Float16* __restrict__ wp){
  int j = i & 7, L = (i >> 3) & 63, rest = i >> 9;
  int nf = rest & 1, s = rest >> 1;
  int k = s*32 + (L >> 4)*8 + j;
  int oc = L & 15;
  int t = k / 48, c = k % 48;
  int dr = (t >> 1) - 1, dc = (t & 1) - 1;
  int ic = c >> 4, pr = (c >> 2) & 3, pc = c & 3;
  float v = 0.f;
  if (nf == 0){
    int kh = 4*dr + pr + 3, kw = 4*dc + pc + 3;
    if (kh >= 0 && kh < 7 && kw >= 0 && kw < 7) v = sw1[((oc*3 + ic)*7 + kh)*7 + kw];
  } else {
    int kh = 4*dr + pr + 1, kw = 4*dc + pc + 1;
    if (kh >= 0 && kh < 3 && kw >= 0 && kw < 3) v = tw1[((oc*3 + ic)*3 + kh)*3 + kw];
  }
  wp[i] = (_Float16)v;
}

// ------- merged conv weight pack: block ranges route to each pack -----------
__global__ __launch_bounds__(256) void wpackAll_k(
    const float* __restrict__ tw3, _Float16* __restrict__ wpk3,
    const float* __restrict__ tw4, _Float16* __restrict__ wpk4,
    const float* __restrict__ tw2, _Float16* __restrict__ wp2,
    const float* __restrict__ sw2, _Float16* __restrict__ wps2,
    const float* __restrict__ sw1, const float* __restrict__ tw1,
    _Float16* __restrict__ wpf){
  const int b = blockIdx.x;
  if (b < 72){
    wpackM_body<32,64>(b*256 + threadIdx.x, tw3, wpk3);
  } else if (b < 360){
    wpackM_body<64,128>((b-72)*256 + threadIdx.x, tw4, wpk4);
  } else if (b < 420){
    wpackS_body<32,5>((b-360)*256 + threadIdx.x, tw2, wp2);
  } else if (b < 444){
    wpackS_body<32,3>((b-420)*256 + threadIdx.x, sw2, wps2);
  } else {
    wpackF_body((b-444)*256 + threadIdx.x, sw1, tw1, wpf);
  }
}

// ------- pack expert GEMM weights W[e][N][K] into frag order, single fp16 ---
template<int KTOT>
__global__ __launch_bounds__(256) void wpackGh_k(const float* __restrict__ w, int N,
    _Float16* __restrict__ wp){
  const int NF = N >> 4, KT = KTOT >> 5;
  const int total = NF * KT * 512;
  const int e = blockIdx.y;
  w  += (size_t)e * N * KTOT;
  wp += (size_t)e * total;
  int i = blockIdx.x*256 + threadIdx.x;
  if (i >= total) return;
  int j = i & 7, L = (i >> 3) & 63, rest = i >> 9;
  int nf = rest % NF, t = rest / NF;
  int n = nf*16 + (L & 15), k = t*32 + (L >> 4)*8 + j;
  wp[i] = (_Float16)w[(size_t)n*KTOT + k];
}

// ---------- fused scout1+conv1, space-to-depth MFMA fp16, SINGLE barrier ----
__global__ __launch_bounds__(256) void fusedM_k(
    const float* __restrict__ x,
    const _Float16* __restrict__ W,
    const float* __restrict__ sb, const float* __restrict__ cb_,
    const float* __restrict__ g, const float* __restrict__ bt,
    const float* __restrict__ mn, const float* __restrict__ vr,
    _Float16* __restrict__ s1out, _Float16* __restrict__ c1out){
  __shared__ __align__(16) _Float16 Ah[3*58*64];
  const int tid = threadIdx.x;
  const int n = blockIdx.x / 28, oh0 = (blockIdx.x % 28) * 2;

  if (tid < 48){
    int rr = tid >> 4, side = (tid >> 3) & 1, q = tid & 7;
    int col = side ? 57 : 0;
    *(int4*)((char*)Ah + (((rr*58 + col) << 7) + q*16)) = (int4){0,0,0,0};
  }

  {
    const int m = tid & 63;
    const bool mok = (m < 56);
    const int cc = m + 1;
    int rc0 = tid >> 6;
    int ic   = (rc0 == 3) ? 0 : rc0;
    int ridx = (rc0 == 3) ? 1 : 0;
    #pragma unroll
    for (int j = 0; j < 9; ++j){
      const int ih = 4*oh0 - 4 + ridx;
      if (mok){
        float4 v = {0.f,0.f,0.f,0.f};
        if (ih >= 0)
          v = *(const float4*)(x + ((size_t)(n*3 + ic)*224 + ih)*224 + 4*m);
        const int rr = ridx >> 2, pr = ridx & 3;
        int boff = (((rr*58 + cc) << 7) + ic*32 + pr*8) ^ ((cc & 7) << 4);
        _Float16 h4[4] = {(_Float16)v.x, (_Float16)v.y, (_Float16)v.z, (_Float16)v.w};
        *(unsigned long long*)((char*)Ah + boff) = *(unsigned long long*)h4;
      }
      ic += 1; ridx += 1;
      if (ic >= 3){ ic -= 3; ridx += 1; }
    }
  }
  __syncthreads();

  const int wid = tid >> 6, lane = tid & 63;
  const int kg8 = (lane >> 4) * 8;
  f32x4 acc[2][2];
  #pragma unroll
  for (int mi = 0; mi < 2; ++mi)
    #pragma unroll
    for (int nf = 0; nf < 2; ++nf) acc[mi][nf] = (f32x4){0.f,0.f,0.f,0.f};

  #pragma unroll
  for (int s = 0; s < 6; ++s){
    const int kk = s*32 + kg8;
    const int t = kk / 48, c0 = kk - t*48;
    const int ra = t >> 1, ca = t & 1;
    f16x8 ah[2];
    #pragma unroll
    for (int mi = 0; mi < 2; ++mi){
      const int m = 2*wid + mi;
      const int rowsel = m >> 2;
      const int ow = (m & 3)*16 + (lane & 15);
      const int owc = ow > 55 ? 55 : ow;
      const int col = owc + ca;
      const int bidx = ((((rowsel + ra)*58 + col) << 7) + c0*2) ^ ((col & 7) << 4);
      ah[mi] = *(const f16x8*)((const char*)Ah + bidx);
    }
    #pragma unroll
    for (int nf = 0; nf < 2; ++nf){
      const f16x8 bw = *(const f16x8*)(W + (s*2 + nf)*512 + lane*8);
      #pragma unroll
      for (int mi = 0; mi < 2; ++mi)
        acc[mi][nf] = __builtin_amdgcn_mfma_f32_16x16x32_f16(ah[mi], bw, acc[mi][nf], 0,0,0);
    }
  }

  const int oc = lane & 15;
  const float sbv = sb[oc];
  const float scv = g[oc] * __frsqrt_rn(vr[oc] + 1e-5f);
  const float mnv = mn[oc], btv = bt[oc], cbv = cb_[oc];
  #pragma unroll
  for (int mi = 0; mi < 2; ++mi){
    const int m = 2*wid + mi;
    const int row = oh0 + (m >> 2);
    const int owb = (m & 3)*16 + (lane >> 4)*4;
    #pragma unroll
    for (int r = 0; r < 4; ++r){
      const int ow = owb + r;
      if (ow >= 56) continue;
      float vs = acc[mi][0][r] + sbv;
      vs = fmaxf((vs - mnv)*scv + btv, 0.f);
      const size_t o = (((size_t)n*56 + row)*56 + ow)*16 + oc;
      s1out[o] = (_Float16)vs;
      c1out[o] = (_Float16)leakyf(acc[mi][1][r] + cbv);
    }
  }
}

// ---------------- strided (S=2) MFMA conv, fp16 NHWC input ------------------
template<int OC,int K,int P,int IH,int IW,int ACT,bool OUT16,bool GATE,bool POOLIN>
__global__ __launch_bounds__(256) void convS_k(
    const _Float16* __restrict__ in,
    const _Float16* __restrict__ W,
    const float* __restrict__ bias,
    const float* __restrict__ bng, const float* __restrict__ bnb,
    const float* __restrict__ bnm, const float* __restrict__ bnv,
    float* __restrict__ outF, _Float16* __restrict__ outH,
    float* __restrict__ gsum){
  constexpr int F = OC/16, KWP = (K+1)/2;
  constexpr int RW = POOLIN ? (IW+1) : IW;
  __shared__ __align__(16) _Float16 A[K*60*16];
  __shared__ float gred[32];

  const int tid = threadIdx.x;
  const int n = blockIdx.x / 28, oh = blockIdx.x % 28;

  if (GATE && tid < 32) gred[tid] = 0.f;

  for (int i = tid; i < K*60*2; i += 256){
    int half = i & 1; int p = i >> 1;
    int c = p % 60; int r = p / 60;
    int ih = 2*oh - P + r, iw = c - P;
    int4 v = {0,0,0,0};
    if (ih >= 0 && ih < IH && iw >= 0 && iw < IW){
      const _Float16* q = in + (((size_t)n*(POOLIN ? IH+1 : IH) + ih)*RW + iw)*16 + half*8;
      if (POOLIN){
        f16x8 a = *(const f16x8*)q;
        f16x8 b = *(const f16x8*)(q + 16);
        f16x8 cc = *(const f16x8*)(q + RW*16);
        f16x8 d = *(const f16x8*)(q + RW*16 + 16);
        f16x8 mx = max8(max8(a, b), max8(cc, d));
        v = *(int4*)&mx;
      } else {
        v = *(const int4*)q;
      }
    }
    int byte = ((r*60 + c)*32 + half*16) ^ (((c>>1)&7) << 4);
    *(int4*)((char*)A + byte) = v;
  }
  __syncthreads();

  const int wid = tid >> 6, lane = tid & 63;
  const int fsel = wid & 1, mb = wid >> 1;
  const int ow_l = min(mb*16 + (lane & 15), 27);
  const int ic0b = ((lane >> 4) & 1) * 16;
  const int kwo  = (lane >> 4) >> 1;

  f32x4 acc = {0.f,0.f,0.f,0.f};
  #pragma unroll
  for (int kh = 0; kh < K; ++kh){
    #pragma unroll
    for (int kwp = 0; kwp < KWP; ++kwp){
      const int kw = 2*kwp + kwo;
      const int c = 2*ow_l + kw;
      int byte = ((kh*60 + c)*32 + ic0b) ^ (((c>>1)&7) << 4);
      f16x8 a = *(const f16x8*)((const char*)A + byte);
      const int s = kh*KWP + kwp;
      const f16x8 b = *(const f16x8*)(W + (s*F + fsel)*512 + lane*8);
      acc = __builtin_amdgcn_mfma_f32_16x16x32_f16(a, b, acc, 0,0,0);
    }
  }

  const int oc = fsel*16 + (lane & 15);
  float bv = bias[oc], sc = 1.f, mm = 0.f, bb = 0.f;
  if (ACT == 1){
    sc = bng[oc] * __frsqrt_rn(bnv[oc] + 1e-5f);
    mm = bnm[oc]; bb = bnb[oc];
  }
  float lsum = 0.f;
  #pragma unroll
  for (int r = 0; r < 4; ++r){
    const int ow = mb*16 + (lane >> 4)*4 + r;
    if (ow >= 28) continue;
    float v = acc[r] + bv;
    if (ACT == 1) v = fmaxf((v - mm)*sc + bb, 0.f);
    else          v = leakyf(v);
    if (GATE){
      lsum += v;
    } else {
      const size_t o = (((size_t)n*28 + oh)*28 + ow)*OC + oc;
      if (OUT16) outH[o] = (_Float16)v;
      else       outF[o] = v;
    }
  }
  if (GATE){
    atomicAdd(&gred[oc], lsum);
    __syncthreads();
    if (tid < 32) atomicAdd(&gsum[n*32 + tid], gred[tid]);
  }
}

// ---------------- MFMA fp16 3x3 s1 p1 conv on 27x27, unpadded NHWC ----------
template<int IC,int OC,bool POOLIN>
__global__ __launch_bounds__(256) void convM_k(
    const _Float16* __restrict__ Ag,
    const _Float16* __restrict__ W,
    const float* __restrict__ bias,
    _Float16* __restrict__ Out)
{
  constexpr int S = IC/32, FTOT = OC/16, FW = FTOT/2;
  constexpr int ICB = IC*2, ICG = ICB/16;
  __shared__ __align__(16) char A[4*34*ICB];

  const int tid = threadIdx.x;
  const int bx = blockIdx.x;
  const int n = bx / 14, pr = bx % 14;
  const int oh0 = pr * 2;

  for (int g = tid; g < 4*34*ICG; g += 256){
    int r = g / (34*ICG);
    int rem = g - r*(34*ICG);
    int c = rem / ICG, q = rem - c*ICG;
    int ir = oh0 + r - 1, icol = c - 1;
    int4 v = {0,0,0,0};
    if (ir >= 0 && ir < 27 && icol >= 0 && icol < 27){
      if (POOLIN){
        const _Float16* p0 = Ag + (((size_t)n*28 + ir)*28 + icol)*IC + q*8;
        f16x8 a = *(const f16x8*)p0;
        f16x8 b = *(const f16x8*)(p0 + IC);
        f16x8 cc = *(const f16x8*)(p0 + 28*IC);
        f16x8 d = *(const f16x8*)(p0 + 28*IC + IC);
        f16x8 mx = max8(max8(a, b), max8(cc, d));
        v = *(int4*)&mx;
      } else {
        v = *(const int4*)(Ag + (((size_t)n*27 + ir)*27 + icol)*IC + q*8);
      }
    }
    int off = (r*34 + c)*ICB + q*16;
    int swz = off ^ ((c & 7) << 4);
    *(int4*)(A + swz) = v;
  }
  __syncthreads();

  const int wid = tid >> 6, lane = tid & 63;
  const int rsel = wid & 1, ocq = wid >> 1;
  const int c0 = lane & 15, kg = (lane >> 4) * 16;
  const int colb0 = c0*ICB + kg, colb1 = (16 + c0)*ICB + kg;
  int msk[3];
  #pragma unroll
  for (int kw = 0; kw < 3; ++kw) msk[kw] = ((c0 + kw) & 7) << 4;

  f32x4 acc[2][FW];
  #pragma unroll
  for (int m = 0; m < 2; ++m)
    #pragma unroll
    for (int f = 0; f < FW; ++f) acc[m][f] = (f32x4){0.f,0.f,0.f,0.f};

  #pragma unroll
  for (int kh = 0; kh < 3; ++kh){
    #pragma unroll
    for (int kw = 0; kw < 3; ++kw){
      #pragma unroll
      for (int s = 0; s < S; ++s){
        const int fr0 = (((kh*3 + kw)*S + s)*FTOT + ocq*FW) * 512 + lane*8;
        f16x8 b[FW];
        #pragma unroll
        for (int f = 0; f < FW; ++f)
          b[f] = *(const f16x8*)(W + fr0 + f*512);
        const int base = ((rsel + kh)*34 + kw)*ICB + s*64;
        const int o0 = (base + colb0) ^ msk[kw];
        const int o1 = (base + colb1) ^ msk[kw];
        f16x8 a0 = *(const f16x8*)(A + o0);
        f16x8 a1 = *(const f16x8*)(A + o1);
        #pragma unroll
        for (int f = 0; f < FW; ++f){
          acc[0][f] = __builtin_amdgcn_mfma_f32_16x16x32_f16(a0, b[f], acc[0][f], 0,0,0);
          acc[1][f] = __builtin_amdgcn_mfma_f32_16x16x32_f16(a1, b[f], acc[1][f], 0,0,0);
        }
      }
    }
  }

  const int orow = oh0 + rsel;
  if (orow >= 27) return;
  #pragma unroll
  for (int f = 0; f < FW; ++f){
    const int oc = (ocq*FW + f)*16 + c0;
    const float bv = bias[oc];
    #pragma unroll
    for (int m = 0; m < 2; ++m){
      #pragma unroll
      for (int r = 0; r < 4; ++r){
        const int ow = m*16 + (lane >> 4)*4 + r;
        if (ow >= 27) continue;
        float v = leakyf(acc[m][f][r] + bv);
        Out[(((size_t)n*27 + orow)*27 + ow)*OC + oc] = (_Float16)v;
      }
    }
  }
}

// ---------------- single-fp16 MFMA GEMM (head layers 1,2) -------------------
template<int KTOT,int ACT>
__global__ __launch_bounds__(256) void gemmH_k(
    const _Float16* __restrict__ A, long strideA,
    const _Float16* __restrict__ W,
    const float* __restrict__ bias, int N,
    _Float16* __restrict__ OutH){
  const int e = blockIdx.z;
  A += (size_t)e * strideA;
  const int NF = N >> 4, KT = KTOT >> 5;
  W += (size_t)e * NF * KT * 512;
  const float* bs = bias + (size_t)e * N;
  const size_t ob = (size_t)e * 256 * N;

  const int tid = threadIdx.x, wid = tid >> 6, lane = tid & 63;
  const int mblk = blockIdx.x * 32;
  const int nf = blockIdx.y * 4 + wid;
  const int r0 = mblk + (lane & 15);
  const int kof = (lane >> 4) * 8;

  f32x4 acc0 = {0,0,0,0}, acc1 = {0,0,0,0};
  for (int t = 0; t < KT; ++t){
    const int k = t*32 + kof;
    f16x8 a0 = *(const f16x8*)(A + (size_t)r0*KTOT + k);
    f16x8 a1 = *(const f16x8*)(A + (size_t)(r0+16)*KTOT + k);
    const f16x8 b = *(const f16x8*)(W + ((size_t)t*NF + nf)*512 + lane*8);
    acc0 = __builtin_amdgcn_mfma_f32_16x16x32_f16(a0, b, acc0, 0,0,0);
    acc1 = __builtin_amdgcn_mfma_f32_16x16x32_f16(a1, b, acc1, 0,0,0);
  }
  const int n = nf*16 + (lane & 15);
  const float bv = bs[n];
  #pragma unroll
  for (int mi = 0; mi < 2; ++mi){
    f32x4 a = mi ? acc1 : acc0;
    #pragma unroll
    for (int r = 0; r < 4; ++r){
      const int m = mblk + mi*16 + (lane >> 4)*4 + r;
      float v = a[r] + bv;
      if (ACT == 1) v = leakyf(v);
      OutH[ob + (size_t)m*N + n] = (_Float16)v;
    }
  }
}

// ------- head layer 3 fused with gated combine: out[b][o] = sum_e w_be*h3 ---
// grid (16, 8): M-tile 16 rows, N-tile 64 (4 waves). Loop e inside (e-order
// identical to old h3+comb path -> bit-identical fp32 result).
__global__ __launch_bounds__(256) void gemmC_k(
    const _Float16* __restrict__ A,      // h2 [3][256][512]
    const _Float16* __restrict__ W,      // ewp3 [3][NF=32][KT=16]*512
    const float* __restrict__ b3,        // eb3 [3][512]
    const float* __restrict__ combw,     // comb [256][3]
    float* __restrict__ out){            // [256][512]
  const int tid = threadIdx.x, wid = tid >> 6, lane = tid & 63;
  const int mblk = blockIdx.x * 16;
  const int nf = blockIdx.y * 4 + wid;
  const int r0 = mblk + (lane & 15);
  const int kof = (lane >> 4) * 8;
  const int n = nf*16 + (lane & 15);

  f32x4 oacc = {0.f,0.f,0.f,0.f};
  #pragma unroll
  for (int e = 0; e < 3; ++e){
    const _Float16* Ae = A + (size_t)e * 256 * 512;
    const _Float16* We = W + (size_t)e * 32 * 16 * 512;
    f32x4 acc = {0.f,0.f,0.f,0.f};
    for (int t = 0; t < 16; ++t){
      f16x8 a = *(const f16x8*)(Ae + (size_t)r0*512 + t*32 + kof);
      const f16x8 b = *(const f16x8*)(We + ((size_t)t*32 + nf)*512 + lane*8);
      acc = __builtin_amdgcn_mfma_f32_16x16x32_f16(a, b, acc, 0,0,0);
    }
    const float bv = b3[e*512 + n];
    #pragma unroll
    for (int r = 0; r < 4; ++r){
      const int m = mblk + (lane >> 4)*4 + r;
      oacc[r] += combw[m*3 + e] * (acc[r] + bv);
    }
  }
  #pragma unroll
  for (int r = 0; r < 4; ++r){
    const int m = mblk + (lane >> 4)*4 + r;
    out[(size_t)m*512 + n] = oacc[r];
  }
}

// ---------------- gate from fused sums: [B,32] -> comb[B,3] -----------------
__global__ __launch_bounds__(256) void gate2_k(const float* __restrict__ gsum,
                                               const float* __restrict__ cw,
                                               const float* __restrict__ cb,
                                               float* __restrict__ comb){
  int n = blockIdx.x * 256 + threadIdx.x;
  if (n >= BATCH) return;
  float mch[32];
  #pragma unroll
  for (int c = 0; c < 32; ++c) mch[c] = gsum[n*32 + c] / 784.f;
  float lg[3];
  #pragma unroll
  for (int e = 0; e < 3; ++e){
    float a = cb[e];
    #pragma unroll
    for (int c = 0; c < 32; ++c) a += mch[c] * cw[e*32 + c];
    lg[e] = a;
  }
  float m = fmaxf(lg[0], fmaxf(lg[1], lg[2]));
  float ex[3], sum = 0.f;
  #pragma unroll
  for (int e = 0; e < 3; ++e){ ex[e] = expf(lg[e] - m); sum += ex[e]; }
  float pr[3];
  #pragma unroll
  for (int e = 0; e < 3; ++e) pr[e] = ex[e] / sum;
  int i1 = 0;
  if (pr[1] > pr[0]) i1 = 1;
  if (pr[2] > pr[i1]) i1 = 2;
  int i2 = -1;
  for (int e = 0; e < 3; ++e){
    if (e == i1) continue;
    if (i2 < 0 || pr[e] > pr[i2]) i2 = e;
  }
  float s12 = pr[i1] + pr[i2] + 1e-6f;
  float cmb[3] = {0.f, 0.f, 0.f};
  cmb[i1] = pr[i1] / s12;
  cmb[i2] = pr[i2] / s12;
  comb[n*3 + 0] = cmb[0];
  comb[n*3 + 1] = cmb[1];
  comb[n*3 + 2] = cmb[2];
}

// ------ channel-parallel fused maxpool2s1(27->26) + adaptive avg(26->3) -----
// writes fp16 flat directly (value identical to old fp32->acvt path)
__global__ __launch_bounds__(256) void papool2_k(const _Float16* __restrict__ in,
                                                 _Float16* __restrict__ flat16){
  __shared__ float red[2][128][9];
  const int n = blockIdx.x;
  const int tid = threadIdx.x;
  const int h = tid >> 7, c = tid & 127;
  const _Float16* p = in + (size_t)n * 729 * 128 + c;

  float sum[9];
  #pragma unroll
  for (int j = 0; j < 9; ++j) sum[j] = 0.f;

  float prev[27], cur[27];
  const int r0 = h * 13;
  #pragma unroll
  for (int rr = 0; rr < 14; ++rr){
    const int r = r0 + rr;
    #pragma unroll
    for (int cc = 0; cc < 27; ++cc)
      cur[cc] = (float)p[(size_t)(r*27 + cc) * 128];
    if (rr > 0){
      const int pr = r - 1;
      const bool b0 = (pr < 9), b1 = (pr >= 8) && (pr < 18), b2 = (pr >= 17);
      #pragma unroll
      for (int cc = 0; cc < 26; ++cc){
        float v = fmaxf(fmaxf(prev[cc], prev[cc+1]), fmaxf(cur[cc], cur[cc+1]));
        if (b0){
          if (cc < 9)             sum[0] += v;
          if (cc >= 8 && cc < 18) sum[1] += v;
          if (cc >= 17)           sum[2] += v;
        }
        if (b1){
          if (cc < 9)             sum[3] += v;
          if (cc >= 8 && cc < 18) sum[4] += v;
          if (cc >= 17)           sum[5] += v;
        }
        if (b2){
          if (cc < 9)             sum[6] += v;
          if (cc >= 8 && cc < 18) sum[7] += v;
          if (cc >= 17)           sum[8] += v;
        }
      }
    }
    #pragma unroll
    for (int cc = 0; cc < 27; ++cc) prev[cc] = cur[cc];
  }

  #pragma unroll
  for (int j = 0; j < 9; ++j) red[h][c][j] = sum[j];
  __syncthreads();

  if (tid < 128){
    const float rcp[9] = {1.f/81, 1.f/90, 1.f/81, 1.f/90, 1.f/100, 1.f/90,
                          1.f/81, 1.f/90, 1.f/81};
    _Float16* o = flat16 + (size_t)n * 1152 + tid * 9;
    #pragma unroll
    for (int j = 0; j < 9; ++j)
      o[j] = (_Float16)((red[0][tid][j] + red[1][tid][j]) * rcp[j]);
  }
}

// ============================================================================
extern "C" void kernel_launch(void* const* d_in, const int* in_sizes, int n_in,
                              void* d_out, int out_size, void* d_ws, size_t ws_size,
                              hipStream_t stream){
  const float* x    = (const float*)d_in[0];
  const float* tw1  = (const float*)d_in[1];  const float* tb1 = (const float*)d_in[2];
  const float* tw2  = (const float*)d_in[3];  const float* tb2 = (const float*)d_in[4];
  const float* tw3  = (const float*)d_in[5];  const float* tb3 = (const float*)d_in[6];
  const float* tw4  = (const float*)d_in[7];  const float* tb4 = (const float*)d_in[8];
  const float* sw1  = (const float*)d_in[9];  const float* sb1 = (const float*)d_in[10];
  const float* bn1g = (const float*)d_in[11]; const float* bn1b = (const float*)d_in[12];
  const float* bn1m = (const float*)d_in[13]; const float* bn1v = (const float*)d_in[14];
  const float* sw2  = (const float*)d_in[15]; const float* sb2 = (const float*)d_in[16];
  const float* bn2g = (const float*)d_in[17]; const float* bn2b = (const float*)d_in[18];
  const float* bn2m = (const float*)d_in[19]; const float* bn2v = (const float*)d_in[20];
  const float* cw   = (const float*)d_in[21]; const float* cb  = (const float*)d_in[22];
  const float* ew1  = (const float*)d_in[23]; const float* eb1 = (const float*)d_in[24];
  const float* ew2  = (const float*)d_in[25]; const float* eb2 = (const float*)d_in[26];
  const float* ew3  = (const float*)d_in[27]; const float* eb3 = (const float*)d_in[28];
  float* out = (float*)d_out;

  // ---- workspace layout (floats), ~157 MB ----
  float* ws = (float*)d_ws;
  size_t off = 0;
  float* comb   = ws + off; off += 768;
  _Float16* flat16 = (_Float16*)(ws + off); off += 147456;  // 294912 fp16
  float* gsum   = ws + off; off += BATCH * 32;
  _Float16* wpk3 = (_Float16*)(ws + off); off += 9216;
  _Float16* wpk4 = (_Float16*)(ws + off); off += 36864;
  _Float16* wp2  = (_Float16*)(ws + off); off += 7680;
  _Float16* wps2 = (_Float16*)(ws + off); off += 3072;
  _Float16* wpf  = (_Float16*)(ws + off); off += 3072;
  off += 16;                                                      // guard pad
  float* bufA   = ws + off; off += 13778944;
  off += 16;                                                      // guard pad
  float* bufB   = ws + off; off += 23887872;
  off += 16;
  (void)ws_size; (void)in_sizes; (void)n_in; (void)out_size;

  // phase aliases (lifetimes disjoint, single-stream ordered)
  _Float16* s1h = (_Float16*)bufA;             // [B,56,56,16] fp16 NHWC
  _Float16* c1h = (_Float16*)bufB;             // [B,56,56,16] fp16 NHWC (25.7MB)
  _Float16* c2h = (_Float16*)(bufB + 14000000);// [B,28,28,32] fp16 NHWC (12.8MB)
  _Float16* C3u = (_Float16*)bufA;             // [B,27,27,64] fp16 unpadded
  _Float16* c4h = (_Float16*)bufB;             // [B,27,27,128] fp16 NHWC

  // head-phase aliases in bufB (valid after papool2_k) — all fp16
  _Float16* hb = (_Float16*)bufB;
  size_t uo = 0;
  _Float16* ewp1 = hb + uo; uo += 3538944;
  _Float16* ewp2 = hb + uo; uo += 1572864;
  _Float16* ewp3 = hb + uo; uo += 786432;
  _Float16* h1   = hb + uo; uo += 786432;
  _Float16* h2   = hb + uo; uo += 393216;

  dim3 blk(256);

  // ---- weight prep (one merged kernel) + gate accumulator zero ----
  hipMemsetAsync(gsum, 0, BATCH * 32 * sizeof(float), stream);
  wpackAll_k<<<dim3(468), blk, 0, stream>>>(
      tw3, wpk3, tw4, wpk4, tw2, wp2, sw2, wps2, sw1, tw1, wpf);

  // ---- fused scout1 + conv1 -> fp16 NHWC ----
  fusedM_k<<<dim3(BATCH*28), blk, 0, stream>>>(
      x, wpf, sb1, tb1, bn1g, bn1b, bn1m, bn1v, s1h, c1h);

  // ---- scout2 fused with gate spatial-sum (no tensor output) ----
  convS_k<32,3,1,56,56,1,false,true,false><<<dim3(BATCH*28), blk, 0, stream>>>(
      s1h, wps2, sb2, bn2g, bn2b, bn2m, bn2v, nullptr, nullptr, gsum);
  gate2_k<<<dim3(1), blk, 0, stream>>>(gsum, cw, cb, comb);

  // ---- conv2 with fused pool1 -> fp16 c2h ----
  convS_k<32,5,2,55,55,0,true,false,true><<<dim3(BATCH*28), blk, 0, stream>>>(
      c1h, wp2, tb2, nullptr, nullptr, nullptr, nullptr, nullptr, c2h, nullptr);

  // ---- conv3 with fused pool2 -> unpadded C3u ----
  convM_k<32,64,true><<<dim3(BATCH*14), blk, 0, stream>>>(
      c2h, wpk3, tb3, C3u);

  // ---- conv4 (unpadded input, predicated staging) -> fp16 c4h ----
  convM_k<64,128,false><<<dim3(BATCH*14), blk, 0, stream>>>(
      C3u, wpk4, tb4, c4h);

  // ---- pool+adaptive-avg -> fp16 flat ----
  papool2_k<<<dim3(BATCH), blk, 0, stream>>>(c4h, flat16);

  // ---- MoE head: pack weights fp16, then GEMMs (layer 3 fused w/ combine) --
  wpackGh_k<1152><<<dim3(4608,3), blk, 0, stream>>>(ew1, 1024, ewp1);
  wpackGh_k<1024><<<dim3(2048,3), blk, 0, stream>>>(ew2,  512, ewp2);
  wpackGh_k< 512><<<dim3(1024,3), blk, 0, stream>>>(ew3,  512, ewp3);

  gemmH_k<1152,1><<<dim3(8,16,3), blk, 0, stream>>>(
      flat16, 0L, ewp1, eb1, 1024, h1);
  gemmH_k<1024,1><<<dim3(8,8,3), blk, 0, stream>>>(
      h1, 256L*1024, ewp2, eb2, 512, h2);
  gemmC_k<<<dim3(16,8), blk, 0, stream>>>(
      h2, ewp3, eb3, comb, out);
}

// Round 22
// 257.058 us; speedup vs baseline: 1.1813x; 1.0345x over previous
//
#include <hip/hip_runtime.h>

#define DEV static __device__ __forceinline__

constexpr int BATCH = 256;

DEV float leakyf(float x){ return x > 0.f ? x : 0.2f * x; }

typedef _Float16 f16x8 __attribute__((ext_vector_type(8)));
typedef float f32x4 __attribute__((ext_vector_type(4)));

DEV f16x8 max8(f16x8 a, f16x8 b){
  f16x8 r;
  #pragma unroll
  for (int j = 0; j < 8; ++j) r[j] = a[j] > b[j] ? a[j] : b[j];
  return r;
}

// ---------------- weight-pack bodies ----------------------------------------
template<int IC,int OC>
DEV void wpackM_body(int i, const float* __restrict__ w, _Float16* __restrict__ wp){
  constexpr int F = OC/16;
  int j = i & 7, L = (i >> 3) & 63, rest = i >> 9;
  int f = rest % F; int q2 = rest / F; int s = q2 % (IC/32); int t = q2 / (IC/32);
  int oc = f*16 + (L & 15), ic = s*32 + (L >> 4)*8 + j;
  wp[i] = (_Float16)w[((size_t)oc*IC + ic)*9 + t];
}

template<int OC,int K>
DEV void wpackS_body(int i, const float* __restrict__ w, _Float16* __restrict__ wp){
  constexpr int F = OC/16, KWP = (K+1)/2;
  int j = i & 7, L = (i >> 3) & 63, rest = i >> 9;
  int f = rest % F, s = rest / F;
  int kh = s / KWP, kwp = s % KWP;
  int k = (L >> 4)*8 + j;
  int kw = 2*kwp + (k >> 4), ic = k & 15;
  int oc = f*16 + (L & 15);
  float v = (kw < K) ? w[((size_t)(oc*16 + ic)*K + kh)*K + kw] : 0.f;
  wp[i] = (_Float16)v;
}

DEV void wpackF_body(int i, const float* __restrict__ sw1,
                     const float* __restrict__ tw1, _Float16* __restrict__ wp){
  int j = i & 7, L = (i >> 3) & 63, rest = i >> 9;
  int nf = rest & 1, s = rest >> 1;
  int k = s*32 + (L >> 4)*8 + j;
  int oc = L & 15;
  int t = k / 48, c = k % 48;
  int dr = (t >> 1) - 1, dc = (t & 1) - 1;
  int ic = c >> 4, pr = (c >> 2) & 3, pc = c & 3;
  float v = 0.f;
  if (nf == 0){
    int kh = 4*dr + pr + 3, kw = 4*dc + pc + 3;
    if (kh >= 0 && kh < 7 && kw >= 0 && kw < 7) v = sw1[((oc*3 + ic)*7 + kh)*7 + kw];
  } else {
    int kh = 4*dr + pr + 1, kw = 4*dc + pc + 1;
    if (kh >= 0 && kh < 3 && kw >= 0 && kw < 3) v = tw1[((oc*3 + ic)*3 + kh)*3 + kw];
  }
  wp[i] = (_Float16)v;
}

template<int KTOT>
DEV void wpackG_body(int i, int e, const float* __restrict__ w, int N,
                     _Float16* __restrict__ wp){
  const int NF = N >> 4;
  const int total = NF * (KTOT >> 5) * 512;
  w  += (size_t)e * N * KTOT;
  wp += (size_t)e * total;
  int j = i & 7, L = (i >> 3) & 63, rest = i >> 9;
  int nf = rest % NF, t = rest / NF;
  int n = nf*16 + (L & 15), k = t*32 + (L >> 4)*8 + j;
  wp[i] = (_Float16)w[(size_t)n*KTOT + k];
}

// ------- mega pack: conv packs + all expert packs in one launch -------------
// blocks: [0,72) wpk3 | [72,360) wpk4 | [360,420) wp2 | [420,444) wps2 |
// [444,468) wpf | then experts: L1 3x4608, L2 3x2048, L3 3x1024.
__global__ __launch_bounds__(256) void wpackX_k(
    const float* __restrict__ tw3, _Float16* __restrict__ wpk3,
    const float* __restrict__ tw4, _Float16* __restrict__ wpk4,
    const float* __restrict__ tw2, _Float16* __restrict__ wp2,
    const float* __restrict__ sw2, _Float16* __restrict__ wps2,
    const float* __restrict__ sw1, const float* __restrict__ tw1,
    _Float16* __restrict__ wpf,
    const float* __restrict__ ew1, _Float16* __restrict__ ewp1,
    const float* __restrict__ ew2, _Float16* __restrict__ ewp2,
    const float* __restrict__ ew3, _Float16* __restrict__ ewp3){
  const int b = blockIdx.x;
  const int tid = threadIdx.x;
  if (b < 72){
    wpackM_body<32,64>(b*256 + tid, tw3, wpk3);
  } else if (b < 360){
    wpackM_body<64,128>((b-72)*256 + tid, tw4, wpk4);
  } else if (b < 420){
    wpackS_body<32,5>((b-360)*256 + tid, tw2, wp2);
  } else if (b < 444){
    wpackS_body<32,3>((b-420)*256 + tid, sw2, wps2);
  } else if (b < 468){
    wpackF_body((b-444)*256 + tid, sw1, tw1, wpf);
  } else {
    int t = b - 468;
    if (t < 13824){
      wpackG_body<1152>((t % 4608)*256 + tid, t / 4608, ew1, 1024, ewp1);
    } else if (t < 19968){
      int t2 = t - 13824;
      wpackG_body<1024>((t2 % 2048)*256 + tid, t2 / 2048, ew2, 512, ewp2);
    } else {
      int t3 = t - 19968;
      wpackG_body<512>((t3 % 1024)*256 + tid, t3 / 1024, ew3, 512, ewp3);
    }
  }
}

// ---------- fused scout1+conv1, space-to-depth MFMA fp16, SINGLE barrier ----
__global__ __launch_bounds__(256) void fusedM_k(
    const float* __restrict__ x,
    const _Float16* __restrict__ W,
    const float* __restrict__ sb, const float* __restrict__ cb_,
    const float* __restrict__ g, const float* __restrict__ bt,
    const float* __restrict__ mn, const float* __restrict__ vr,
    _Float16* __restrict__ s1out, _Float16* __restrict__ c1out){
  __shared__ __align__(16) _Float16 Ah[3*58*64];
  const int tid = threadIdx.x;
  const int n = blockIdx.x / 28, oh0 = (blockIdx.x % 28) * 2;

  if (tid < 48){
    int rr = tid >> 4, side = (tid >> 3) & 1, q = tid & 7;
    int col = side ? 57 : 0;
    *(int4*)((char*)Ah + (((rr*58 + col) << 7) + q*16)) = (int4){0,0,0,0};
  }

  {
    const int m = tid & 63;
    const bool mok = (m < 56);
    const int cc = m + 1;
    int rc0 = tid >> 6;
    int ic   = (rc0 == 3) ? 0 : rc0;
    int ridx = (rc0 == 3) ? 1 : 0;
    #pragma unroll
    for (int j = 0; j < 9; ++j){
      const int ih = 4*oh0 - 4 + ridx;
      if (mok){
        float4 v = {0.f,0.f,0.f,0.f};
        if (ih >= 0)
          v = *(const float4*)(x + ((size_t)(n*3 + ic)*224 + ih)*224 + 4*m);
        const int rr = ridx >> 2, pr = ridx & 3;
        int boff = (((rr*58 + cc) << 7) + ic*32 + pr*8) ^ ((cc & 7) << 4);
        _Float16 h4[4] = {(_Float16)v.x, (_Float16)v.y, (_Float16)v.z, (_Float16)v.w};
        *(unsigned long long*)((char*)Ah + boff) = *(unsigned long long*)h4;
      }
      ic += 1; ridx += 1;
      if (ic >= 3){ ic -= 3; ridx += 1; }
    }
  }
  __syncthreads();

  const int wid = tid >> 6, lane = tid & 63;
  const int kg8 = (lane >> 4) * 8;
  f32x4 acc[2][2];
  #pragma unroll
  for (int mi = 0; mi < 2; ++mi)
    #pragma unroll
    for (int nf = 0; nf < 2; ++nf) acc[mi][nf] = (f32x4){0.f,0.f,0.f,0.f};

  #pragma unroll
  for (int s = 0; s < 6; ++s){
    const int kk = s*32 + kg8;
    const int t = kk / 48, c0 = kk - t*48;
    const int ra = t >> 1, ca = t & 1;
    f16x8 ah[2];
    #pragma unroll
    for (int mi = 0; mi < 2; ++mi){
      const int m = 2*wid + mi;
      const int rowsel = m >> 2;
      const int ow = (m & 3)*16 + (lane & 15);
      const int owc = ow > 55 ? 55 : ow;
      const int col = owc + ca;
      const int bidx = ((((rowsel + ra)*58 + col) << 7) + c0*2) ^ ((col & 7) << 4);
      ah[mi] = *(const f16x8*)((const char*)Ah + bidx);
    }
    #pragma unroll
    for (int nf = 0; nf < 2; ++nf){
      const f16x8 bw = *(const f16x8*)(W + (s*2 + nf)*512 + lane*8);
      #pragma unroll
      for (int mi = 0; mi < 2; ++mi)
        acc[mi][nf] = __builtin_amdgcn_mfma_f32_16x16x32_f16(ah[mi], bw, acc[mi][nf], 0,0,0);
    }
  }

  const int oc = lane & 15;
  const float sbv = sb[oc];
  const float scv = g[oc] * __frsqrt_rn(vr[oc] + 1e-5f);
  const float mnv = mn[oc], btv = bt[oc], cbv = cb_[oc];
  #pragma unroll
  for (int mi = 0; mi < 2; ++mi){
    const int m = 2*wid + mi;
    const int row = oh0 + (m >> 2);
    const int owb = (m & 3)*16 + (lane >> 4)*4;
    #pragma unroll
    for (int r = 0; r < 4; ++r){
      const int ow = owb + r;
      if (ow >= 56) continue;
      float vs = acc[mi][0][r] + sbv;
      vs = fmaxf((vs - mnv)*scv + btv, 0.f);
      const size_t o = (((size_t)n*56 + row)*56 + ow)*16 + oc;
      s1out[o] = (_Float16)vs;
      c1out[o] = (_Float16)leakyf(acc[mi][1][r] + cbv);
    }
  }
}

// ---------------- strided (S=2) MFMA conv body ------------------------------
template<int OC,int K,int P,int IH,int IW,int ACT,bool OUT16,bool GATE,bool POOLIN>
DEV void convS_body(int bx, int tid, _Float16* A, float* gred,
    const _Float16* __restrict__ in,
    const _Float16* __restrict__ W,
    const float* __restrict__ bias,
    const float* __restrict__ bng, const float* __restrict__ bnb,
    const float* __restrict__ bnm, const float* __restrict__ bnv,
    float* __restrict__ outF, _Float16* __restrict__ outH,
    float* __restrict__ gsum){
  constexpr int F = OC/16, KWP = (K+1)/2;
  constexpr int RW = POOLIN ? (IW+1) : IW;

  const int n = bx / 28, oh = bx % 28;

  if (GATE && tid < 32) gred[tid] = 0.f;

  for (int i = tid; i < K*60*2; i += 256){
    int half = i & 1; int p = i >> 1;
    int c = p % 60; int r = p / 60;
    int ih = 2*oh - P + r, iw = c - P;
    int4 v = {0,0,0,0};
    if (ih >= 0 && ih < IH && iw >= 0 && iw < IW){
      const _Float16* q = in + (((size_t)n*(POOLIN ? IH+1 : IH) + ih)*RW + iw)*16 + half*8;
      if (POOLIN){
        f16x8 a = *(const f16x8*)q;
        f16x8 b = *(const f16x8*)(q + 16);
        f16x8 cc = *(const f16x8*)(q + RW*16);
        f16x8 d = *(const f16x8*)(q + RW*16 + 16);
        f16x8 mx = max8(max8(a, b), max8(cc, d));
        v = *(int4*)&mx;
      } else {
        v = *(const int4*)q;
      }
    }
    int byte = ((r*60 + c)*32 + half*16) ^ (((c>>1)&7) << 4);
    *(int4*)((char*)A + byte) = v;
  }
  __syncthreads();

  const int wid = tid >> 6, lane = tid & 63;
  const int fsel = wid & 1, mb = wid >> 1;
  const int ow_l = min(mb*16 + (lane & 15), 27);
  const int ic0b = ((lane >> 4) & 1) * 16;
  const int kwo  = (lane >> 4) >> 1;

  f32x4 acc = {0.f,0.f,0.f,0.f};
  #pragma unroll
  for (int kh = 0; kh < K; ++kh){
    #pragma unroll
    for (int kwp = 0; kwp < KWP; ++kwp){
      const int kw = 2*kwp + kwo;
      const int c = 2*ow_l + kw;
      int byte = ((kh*60 + c)*32 + ic0b) ^ (((c>>1)&7) << 4);
      f16x8 a = *(const f16x8*)((const char*)A + byte);
      const int s = kh*KWP + kwp;
      const f16x8 b = *(const f16x8*)(W + (s*F + fsel)*512 + lane*8);
      acc = __builtin_amdgcn_mfma_f32_16x16x32_f16(a, b, acc, 0,0,0);
    }
  }

  const int oc = fsel*16 + (lane & 15);
  float bv = bias[oc], sc = 1.f, mm = 0.f, bb = 0.f;
  if (ACT == 1){
    sc = bng[oc] * __frsqrt_rn(bnv[oc] + 1e-5f);
    mm = bnm[oc]; bb = bnb[oc];
  }
  float lsum = 0.f;
  #pragma unroll
  for (int r = 0; r < 4; ++r){
    const int ow = mb*16 + (lane >> 4)*4 + r;
    if (ow >= 28) continue;
    float v = acc[r] + bv;
    if (ACT == 1) v = fmaxf((v - mm)*sc + bb, 0.f);
    else          v = leakyf(v);
    if (GATE){
      lsum += v;
    } else {
      const size_t o = (((size_t)n*28 + oh)*28 + ow)*OC + oc;
      if (OUT16) outH[o] = (_Float16)v;
      else       outF[o] = v;
    }
  }
  if (GATE){
    atomicAdd(&gred[oc], lsum);
    __syncthreads();
    if (tid < 32) atomicAdd(&gsum[n*32 + tid], gred[tid]);
  }
}

// ------- merged scout2(GATE) + conv2(POOLIN): independent, co-resident ------
__global__ __launch_bounds__(256) void convSS_k(
    const _Float16* __restrict__ s1h, const _Float16* __restrict__ wps2,
    const float* __restrict__ sb2,
    const float* __restrict__ bn2g, const float* __restrict__ bn2b,
    const float* __restrict__ bn2m, const float* __restrict__ bn2v,
    float* __restrict__ gsum,
    const _Float16* __restrict__ c1h, const _Float16* __restrict__ wp2,
    const float* __restrict__ tb2, _Float16* __restrict__ c2h){
  __shared__ __align__(16) _Float16 A[5*60*16];
  __shared__ float gred[32];
  const int tid = threadIdx.x;
  if (blockIdx.x < BATCH*28){
    convS_body<32,3,1,56,56,1,false,true,false>(blockIdx.x, tid, A, gred,
        s1h, wps2, sb2, bn2g, bn2b, bn2m, bn2v, nullptr, nullptr, gsum);
  } else {
    convS_body<32,5,2,55,55,0,true,false,true>(blockIdx.x - BATCH*28, tid, A, gred,
        c1h, wp2, tb2, nullptr, nullptr, nullptr, nullptr, nullptr, c2h, nullptr);
  }
}

// ---------------- MFMA fp16 3x3 s1 p1 conv on 27x27, unpadded NHWC ----------
template<int IC,int OC,bool POOLIN>
__global__ __launch_bounds__(256) void convM_k(
    const _Float16* __restrict__ Ag,
    const _Float16* __restrict__ W,
    const float* __restrict__ bias,
    _Float16* __restrict__ Out)
{
  constexpr int S = IC/32, FTOT = OC/16, FW = FTOT/2;
  constexpr int ICB = IC*2, ICG = ICB/16;
  __shared__ __align__(16) char A[4*34*ICB];

  const int tid = threadIdx.x;
  const int bx = blockIdx.x;
  const int n = bx / 14, pr = bx % 14;
  const int oh0 = pr * 2;

  for (int g = tid; g < 4*34*ICG; g += 256){
    int r = g / (34*ICG);
    int rem = g - r*(34*ICG);
    int c = rem / ICG, q = rem - c*ICG;
    int ir = oh0 + r - 1, icol = c - 1;
    int4 v = {0,0,0,0};
    if (ir >= 0 && ir < 27 && icol >= 0 && icol < 27){
      if (POOLIN){
        const _Float16* p0 = Ag + (((size_t)n*28 + ir)*28 + icol)*IC + q*8;
        f16x8 a = *(const f16x8*)p0;
        f16x8 b = *(const f16x8*)(p0 + IC);
        f16x8 cc = *(const f16x8*)(p0 + 28*IC);
        f16x8 d = *(const f16x8*)(p0 + 28*IC + IC);
        f16x8 mx = max8(max8(a, b), max8(cc, d));
        v = *(int4*)&mx;
      } else {
        v = *(const int4*)(Ag + (((size_t)n*27 + ir)*27 + icol)*IC + q*8);
      }
    }
    int off = (r*34 + c)*ICB + q*16;
    int swz = off ^ ((c & 7) << 4);
    *(int4*)(A + swz) = v;
  }
  __syncthreads();

  const int wid = tid >> 6, lane = tid & 63;
  const int rsel = wid & 1, ocq = wid >> 1;
  const int c0 = lane & 15, kg = (lane >> 4) * 16;
  const int colb0 = c0*ICB + kg, colb1 = (16 + c0)*ICB + kg;
  int msk[3];
  #pragma unroll
  for (int kw = 0; kw < 3; ++kw) msk[kw] = ((c0 + kw) & 7) << 4;

  f32x4 acc[2][FW];
  #pragma unroll
  for (int m = 0; m < 2; ++m)
    #pragma unroll
    for (int f = 0; f < FW; ++f) acc[m][f] = (f32x4){0.f,0.f,0.f,0.f};

  #pragma unroll
  for (int kh = 0; kh < 3; ++kh){
    #pragma unroll
    for (int kw = 0; kw < 3; ++kw){
      #pragma unroll
      for (int s = 0; s < S; ++s){
        const int fr0 = (((kh*3 + kw)*S + s)*FTOT + ocq*FW) * 512 + lane*8;
        f16x8 b[FW];
        #pragma unroll
        for (int f = 0; f < FW; ++f)
          b[f] = *(const f16x8*)(W + fr0 + f*512);
        const int base = ((rsel + kh)*34 + kw)*ICB + s*64;
        const int o0 = (base + colb0) ^ msk[kw];
        const int o1 = (base + colb1) ^ msk[kw];
        f16x8 a0 = *(const f16x8*)(A + o0);
        f16x8 a1 = *(const f16x8*)(A + o1);
        #pragma unroll
        for (int f = 0; f < FW; ++f){
          acc[0][f] = __builtin_amdgcn_mfma_f32_16x16x32_f16(a0, b[f], acc[0][f], 0,0,0);
          acc[1][f] = __builtin_amdgcn_mfma_f32_16x16x32_f16(a1, b[f], acc[1][f], 0,0,0);
        }
      }
    }
  }

  const int orow = oh0 + rsel;
  if (orow >= 27) return;
  #pragma unroll
  for (int f = 0; f < FW; ++f){
    const int oc = (ocq*FW + f)*16 + c0;
    const float bv = bias[oc];
    #pragma unroll
    for (int m = 0; m < 2; ++m){
      #pragma unroll
      for (int r = 0; r < 4; ++r){
        const int ow = m*16 + (lane >> 4)*4 + r;
        if (ow >= 27) continue;
        float v = leakyf(acc[m][f][r] + bv);
        Out[(((size_t)n*27 + orow)*27 + ow)*OC + oc] = (_Float16)v;
      }
    }
  }
}

// ---------------- single-fp16 MFMA GEMM (head layers 1,2) -------------------
template<int KTOT,int ACT>
__global__ __launch_bounds__(256) void gemmH_k(
    const _Float16* __restrict__ A, long strideA,
    const _Float16* __restrict__ W,
    const float* __restrict__ bias, int N,
    _Float16* __restrict__ OutH){
  const int e = blockIdx.z;
  A += (size_t)e * strideA;
  const int NF = N >> 4, KT = KTOT >> 5;
  W += (size_t)e * NF * KT * 512;
  const float* bs = bias + (size_t)e * N;
  const size_t ob = (size_t)e * 256 * N;

  const int tid = threadIdx.x, wid = tid >> 6, lane = tid & 63;
  const int mblk = blockIdx.x * 32;
  const int nf = blockIdx.y * 4 + wid;
  const int r0 = mblk + (lane & 15);
  const int kof = (lane >> 4) * 8;

  f32x4 acc0 = {0,0,0,0}, acc1 = {0,0,0,0};
  for (int t = 0; t < KT; ++t){
    const int k = t*32 + kof;
    f16x8 a0 = *(const f16x8*)(A + (size_t)r0*KTOT + k);
    f16x8 a1 = *(const f16x8*)(A + (size_t)(r0+16)*KTOT + k);
    const f16x8 b = *(const f16x8*)(W + ((size_t)t*NF + nf)*512 + lane*8);
    acc0 = __builtin_amdgcn_mfma_f32_16x16x32_f16(a0, b, acc0, 0,0,0);
    acc1 = __builtin_amdgcn_mfma_f32_16x16x32_f16(a1, b, acc1, 0,0,0);
  }
  const int n = nf*16 + (lane & 15);
  const float bv = bs[n];
  #pragma unroll
  for (int mi = 0; mi < 2; ++mi){
    f32x4 a = mi ? acc1 : acc0;
    #pragma unroll
    for (int r = 0; r < 4; ++r){
      const int m = mblk + mi*16 + (lane >> 4)*4 + r;
      float v = a[r] + bv;
      if (ACT == 1) v = leakyf(v);
      OutH[ob + (size_t)m*N + n] = (_Float16)v;
    }
  }
}

// ------- head layer 3 + per-block gate + gated combine ----------------------
// grid (16, 8). Gate recomputed per block for its 16 rows (same arithmetic
// order as old gate2_k -> bit-identical).
__global__ __launch_bounds__(256) void gemmC_k(
    const _Float16* __restrict__ A,      // h2 [3][256][512]
    const _Float16* __restrict__ W,      // ewp3 [3][32][16]*512
    const float* __restrict__ b3,        // eb3 [3][512]
    const float* __restrict__ gsum,      // [256][32]
    const float* __restrict__ cw, const float* __restrict__ cb,
    float* __restrict__ out){            // [256][512]
  __shared__ float combL[16][3];
  const int tid = threadIdx.x, wid = tid >> 6, lane = tid & 63;
  const int mblk = blockIdx.x * 16;

  if (tid < 16){
    const int n = mblk + tid;
    float mch[32];
    #pragma unroll
    for (int c = 0; c < 32; ++c) mch[c] = gsum[n*32 + c] / 784.f;
    float lg[3];
    #pragma unroll
    for (int e = 0; e < 3; ++e){
      float a = cb[e];
      #pragma unroll
      for (int c = 0; c < 32; ++c) a += mch[c] * cw[e*32 + c];
      lg[e] = a;
    }
    float m = fmaxf(lg[0], fmaxf(lg[1], lg[2]));
    float ex[3], sum = 0.f;
    #pragma unroll
    for (int e = 0; e < 3; ++e){ ex[e] = expf(lg[e] - m); sum += ex[e]; }
    float pr[3];
    #pragma unroll
    for (int e = 0; e < 3; ++e) pr[e] = ex[e] / sum;
    int i1 = 0;
    if (pr[1] > pr[0]) i1 = 1;
    if (pr[2] > pr[i1]) i1 = 2;
    int i2 = -1;
    for (int e = 0; e < 3; ++e){
      if (e == i1) continue;
      if (i2 < 0 || pr[e] > pr[i2]) i2 = e;
    }
    float s12 = pr[i1] + pr[i2] + 1e-6f;
    float cmb[3] = {0.f, 0.f, 0.f};
    cmb[i1] = pr[i1] / s12;
    cmb[i2] = pr[i2] / s12;
    combL[tid][0] = cmb[0];
    combL[tid][1] = cmb[1];
    combL[tid][2] = cmb[2];
  }
  __syncthreads();

  const int nf = blockIdx.y * 4 + wid;
  const int r0 = mblk + (lane & 15);
  const int kof = (lane >> 4) * 8;
  const int n = nf*16 + (lane & 15);

  f32x4 oacc = {0.f,0.f,0.f,0.f};
  #pragma unroll
  for (int e = 0; e < 3; ++e){
    const _Float16* Ae = A + (size_t)e * 256 * 512;
    const _Float16* We = W + (size_t)e * 32 * 16 * 512;
    f32x4 acc = {0.f,0.f,0.f,0.f};
    for (int t = 0; t < 16; ++t){
      f16x8 a = *(const f16x8*)(Ae + (size_t)r0*512 + t*32 + kof);
      const f16x8 b = *(const f16x8*)(We + ((size_t)t*32 + nf)*512 + lane*8);
      acc = __builtin_amdgcn_mfma_f32_16x16x32_f16(a, b, acc, 0,0,0);
    }
    const float bv = b3[e*512 + n];
    #pragma unroll
    for (int r = 0; r < 4; ++r){
      const int lr = (lane >> 4)*4 + r;
      oacc[r] += combL[lr][e] * (acc[r] + bv);
    }
  }
  #pragma unroll
  for (int r = 0; r < 4; ++r){
    const int m = mblk + (lane >> 4)*4 + r;
    out[(size_t)m*512 + n] = oacc[r];
  }
}

// ------ channel-parallel fused maxpool2s1(27->26) + adaptive avg(26->3) -----
__global__ __launch_bounds__(256) void papool2_k(const _Float16* __restrict__ in,
                                                 _Float16* __restrict__ flat16){
  __shared__ float red[2][128][9];
  const int n = blockIdx.x;
  const int tid = threadIdx.x;
  const int h = tid >> 7, c = tid & 127;
  const _Float16* p = in + (size_t)n * 729 * 128 + c;

  float sum[9];
  #pragma unroll
  for (int j = 0; j < 9; ++j) sum[j] = 0.f;

  float prev[27], cur[27];
  const int r0 = h * 13;
  #pragma unroll
  for (int rr = 0; rr < 14; ++rr){
    const int r = r0 + rr;
    #pragma unroll
    for (int cc = 0; cc < 27; ++cc)
      cur[cc] = (float)p[(size_t)(r*27 + cc) * 128];
    if (rr > 0){
      const int pr = r - 1;
      const bool b0 = (pr < 9), b1 = (pr >= 8) && (pr < 18), b2 = (pr >= 17);
      #pragma unroll
      for (int cc = 0; cc < 26; ++cc){
        float v = fmaxf(fmaxf(prev[cc], prev[cc+1]), fmaxf(cur[cc], cur[cc+1]));
        if (b0){
          if (cc < 9)             sum[0] += v;
          if (cc >= 8 && cc < 18) sum[1] += v;
          if (cc >= 17)           sum[2] += v;
        }
        if (b1){
          if (cc < 9)             sum[3] += v;
          if (cc >= 8 && cc < 18) sum[4] += v;
          if (cc >= 17)           sum[5] += v;
        }
        if (b2){
          if (cc < 9)             sum[6] += v;
          if (cc >= 8 && cc < 18) sum[7] += v;
          if (cc >= 17)           sum[8] += v;
        }
      }
    }
    #pragma unroll
    for (int cc = 0; cc < 27; ++cc) prev[cc] = cur[cc];
  }

  #pragma unroll
  for (int j = 0; j < 9; ++j) red[h][c][j] = sum[j];
  __syncthreads();

  if (tid < 128){
    const float rcp[9] = {1.f/81, 1.f/90, 1.f/81, 1.f/90, 1.f/100, 1.f/90,
                          1.f/81, 1.f/90, 1.f/81};
    _Float16* o = flat16 + (size_t)n * 1152 + tid * 9;
    #pragma unroll
    for (int j = 0; j < 9; ++j)
      o[j] = (_Float16)((red[0][tid][j] + red[1][tid][j]) * rcp[j]);
  }
}

// ============================================================================
extern "C" void kernel_launch(void* const* d_in, const int* in_sizes, int n_in,
                              void* d_out, int out_size, void* d_ws, size_t ws_size,
                              hipStream_t stream){
  const float* x    = (const float*)d_in[0];
  const float* tw1  = (const float*)d_in[1];  const float* tb1 = (const float*)d_in[2];
  const float* tw2  = (const float*)d_in[3];  const float* tb2 = (const float*)d_in[4];
  const float* tw3  = (const float*)d_in[5];  const float* tb3 = (const float*)d_in[6];
  const float* tw4  = (const float*)d_in[7];  const float* tb4 = (const float*)d_in[8];
  const float* sw1  = (const float*)d_in[9];  const float* sb1 = (const float*)d_in[10];
  const float* bn1g = (const float*)d_in[11]; const float* bn1b = (const float*)d_in[12];
  const float* bn1m = (const float*)d_in[13]; const float* bn1v = (const float*)d_in[14];
  const float* sw2  = (const float*)d_in[15]; const float* sb2 = (const float*)d_in[16];
  const float* bn2g = (const float*)d_in[17]; const float* bn2b = (const float*)d_in[18];
  const float* bn2m = (const float*)d_in[19]; const float* bn2v = (const float*)d_in[20];
  const float* cw   = (const float*)d_in[21]; const float* cb  = (const float*)d_in[22];
  const float* ew1  = (const float*)d_in[23]; const float* eb1 = (const float*)d_in[24];
  const float* ew2  = (const float*)d_in[25]; const float* eb2 = (const float*)d_in[26];
  const float* ew3  = (const float*)d_in[27]; const float* eb3 = (const float*)d_in[28];
  float* out = (float*)d_out;

  // ---- workspace layout (floats), ~157 MB ----
  float* ws = (float*)d_ws;
  size_t off = 0;
  _Float16* flat16 = (_Float16*)(ws + off); off += 147456;
  float* gsum   = ws + off; off += BATCH * 32;
  _Float16* wpk3 = (_Float16*)(ws + off); off += 9216;
  _Float16* wpk4 = (_Float16*)(ws + off); off += 36864;
  _Float16* wp2  = (_Float16*)(ws + off); off += 7680;
  _Float16* wps2 = (_Float16*)(ws + off); off += 3072;
  _Float16* wpf  = (_Float16*)(ws + off); off += 3072;
  off += 16;                                                      // guard pad
  float* bufA   = ws + off; off += 13778944;
  off += 16;                                                      // guard pad
  float* bufB   = ws + off; off += 23887872;
  off += 16;
  (void)ws_size; (void)in_sizes; (void)n_in; (void)out_size;

  // bufA aliases: s1h [0, 6,422,528 floats) ; C3u [0, 5,971,968) (later) ;
  // expert packed weights parked at float offset 6,500,000 (disjoint from both)
  _Float16* s1h = (_Float16*)bufA;             // [B,56,56,16] fp16
  _Float16* C3u = (_Float16*)bufA;             // [B,27,27,64] fp16 (after s1h dead)
  _Float16* ewp1 = (_Float16*)(bufA + 6500000);           // 3,538,944 fp16
  _Float16* ewp2 = ewp1 + 3538944;                        // 1,572,864 fp16
  _Float16* ewp3 = ewp2 + 1572864;                        //   786,432 fp16
  // bufB aliases
  _Float16* c1h = (_Float16*)bufB;             // [B,56,56,16] fp16 (25.7MB)
  _Float16* c2h = (_Float16*)(bufB + 14000000);// [B,28,28,32] fp16 (12.8MB)
  _Float16* c4h = (_Float16*)bufB;             // [B,27,27,128] fp16 (23.9MB)
  _Float16* h1  = (_Float16*)bufB;             // [3][256][1024] fp16 (after c4h dead)
  _Float16* h2  = h1 + 786432;                 // [3][256][512] fp16

  dim3 blk(256);

  // ---- gate accumulator zero + ALL weight packing in one kernel ----
  hipMemsetAsync(gsum, 0, BATCH * 32 * sizeof(float), stream);
  wpackX_k<<<dim3(23508), blk, 0, stream>>>(
      tw3, wpk3, tw4, wpk4, tw2, wp2, sw2, wps2, sw1, tw1, wpf,
      ew1, ewp1, ew2, ewp2, ew3, ewp3);

  // ---- fused scout1 + conv1 -> fp16 NHWC ----
  fusedM_k<<<dim3(BATCH*28), blk, 0, stream>>>(
      x, wpf, sb1, tb1, bn1g, bn1b, bn1m, bn1v, s1h, c1h);

  // ---- merged scout2(gate-sum) + conv2(fused pool1) ----
  convSS_k<<<dim3(BATCH*28*2), blk, 0, stream>>>(
      s1h, wps2, sb2, bn2g, bn2b, bn2m, bn2v, gsum,
      c1h, wp2, tb2, c2h);

  // ---- conv3 with fused pool2 -> unpadded C3u ----
  convM_k<32,64,true><<<dim3(BATCH*14), blk, 0, stream>>>(
      c2h, wpk3, tb3, C3u);

  // ---- conv4 (unpadded input, predicated staging) -> fp16 c4h ----
  convM_k<64,128,false><<<dim3(BATCH*14), blk, 0, stream>>>(
      C3u, wpk4, tb4, c4h);

  // ---- pool+adaptive-avg -> fp16 flat ----
  papool2_k<<<dim3(BATCH), blk, 0, stream>>>(c4h, flat16);

  // ---- MoE head GEMMs (layer 3 fused with gate + combine) ----
  gemmH_k<1152,1><<<dim3(8,16,3), blk, 0, stream>>>(
      flat16, 0L, ewp1, eb1, 1024, h1);
  gemmH_k<1024,1><<<dim3(8,8,3), blk, 0, stream>>>(
      h1, 256L*1024, ewp2, eb2, 512, h2);
  gemmC_k<<<dim3(16,8), blk, 0, stream>>>(
      h2, ewp3, eb3, gsum, cw, cb, out);
}

// Round 23
// 246.862 us; speedup vs baseline: 1.2301x; 1.0413x over previous
//
#include <hip/hip_runtime.h>

#define DEV static __device__ __forceinline__

constexpr int BATCH = 256;

DEV float leakyf(float x){ return x > 0.f ? x : 0.2f * x; }

typedef _Float16 f16x8 __attribute__((ext_vector_type(8)));
typedef float f32x4 __attribute__((ext_vector_type(4)));

DEV f16x8 max8(f16x8 a, f16x8 b){
  f16x8 r;
  #pragma unroll
  for (int j = 0; j < 8; ++j) r[j] = a[j] > b[j] ? a[j] : b[j];
  return r;
}

// ---------------- weight-pack bodies ----------------------------------------
template<int IC,int OC>
DEV void wpackM_body(int i, const float* __restrict__ w, _Float16* __restrict__ wp){
  constexpr int F = OC/16;
  int j = i & 7, L = (i >> 3) & 63, rest = i >> 9;
  int f = rest % F; int q2 = rest / F; int s = q2 % (IC/32); int t = q2 / (IC/32);
  int oc = f*16 + (L & 15), ic = s*32 + (L >> 4)*8 + j;
  wp[i] = (_Float16)w[((size_t)oc*IC + ic)*9 + t];
}

template<int OC,int K>
DEV void wpackS_body(int i, const float* __restrict__ w, _Float16* __restrict__ wp){
  constexpr int F = OC/16, KWP = (K+1)/2;
  int j = i & 7, L = (i >> 3) & 63, rest = i >> 9;
  int f = rest % F, s = rest / F;
  int kh = s / KWP, kwp = s % KWP;
  int k = (L >> 4)*8 + j;
  int kw = 2*kwp + (k >> 4), ic = k & 15;
  int oc = f*16 + (L & 15);
  float v = (kw < K) ? w[((size_t)(oc*16 + ic)*K + kh)*K + kw] : 0.f;
  wp[i] = (_Float16)v;
}

DEV void wpackF_body(int i, const float* __restrict__ sw1,
                     const float* __restrict__ tw1, _Float16* __restrict__ wp){
  int j = i & 7, L = (i >> 3) & 63, rest = i >> 9;
  int nf = rest & 1, s = rest >> 1;
  int k = s*32 + (L >> 4)*8 + j;
  int oc = L & 15;
  int t = k / 48, c = k % 48;
  int dr = (t >> 1) - 1, dc = (t & 1) - 1;
  int ic = c >> 4, pr = (c >> 2) & 3, pc = c & 3;
  float v = 0.f;
  if (nf == 0){
    int kh = 4*dr + pr + 3, kw = 4*dc + pc + 3;
    if (kh >= 0 && kh < 7 && kw >= 0 && kw < 7) v = sw1[((oc*3 + ic)*7 + kh)*7 + kw];
  } else {
    int kh = 4*dr + pr + 1, kw = 4*dc + pc + 1;
    if (kh >= 0 && kh < 3 && kw >= 0 && kw < 3) v = tw1[((oc*3 + ic)*3 + kh)*3 + kw];
  }
  wp[i] = (_Float16)v;
}

template<int KTOT>
DEV void wpackG_body(int i, int e, const float* __restrict__ w, int N,
                     _Float16* __restrict__ wp){
  const int NF = N >> 4;
  const int total = NF * (KTOT >> 5) * 512;
  w  += (size_t)e * N * KTOT;
  wp += (size_t)e * total;
  int j = i & 7, L = (i >> 3) & 63, rest = i >> 9;
  int nf = rest % NF, t = rest / NF;
  int n = nf*16 + (L & 15), k = t*32 + (L >> 4)*8 + j;
  wp[i] = (_Float16)w[(size_t)n*KTOT + k];
}

// ------- conv weight packs + gsum zero, one small kernel --------------------
// blocks: [0,72) wpk3 | [72,360) wpk4 | [360,420) wp2 | [420,444) wps2 |
// [444,468) wpf | [468,500) zero gsum (8192 floats)
__global__ __launch_bounds__(256) void wpackC_k(
    const float* __restrict__ tw3, _Float16* __restrict__ wpk3,
    const float* __restrict__ tw4, _Float16* __restrict__ wpk4,
    const float* __restrict__ tw2, _Float16* __restrict__ wp2,
    const float* __restrict__ sw2, _Float16* __restrict__ wps2,
    const float* __restrict__ sw1, const float* __restrict__ tw1,
    _Float16* __restrict__ wpf, float* __restrict__ gsum){
  const int b = blockIdx.x;
  const int tid = threadIdx.x;
  if (b < 72){
    wpackM_body<32,64>(b*256 + tid, tw3, wpk3);
  } else if (b < 360){
    wpackM_body<64,128>((b-72)*256 + tid, tw4, wpk4);
  } else if (b < 420){
    wpackS_body<32,5>((b-360)*256 + tid, tw2, wp2);
  } else if (b < 444){
    wpackS_body<32,3>((b-420)*256 + tid, sw2, wps2);
  } else if (b < 468){
    wpackF_body((b-444)*256 + tid, sw1, tw1, wpf);
  } else {
    gsum[(b-468)*256 + tid] = 0.f;
  }
}

// ---------- merged expert packs (first) + fused scout1+conv1 MFMA -----------
// blocks [0,23040): expert weight packs (streaming; drain early, hide under
// conv blocks). blocks [23040,30208): fusedM with XCD-swizzled work-id.
__global__ __launch_bounds__(256) void fusedX_k(
    const float* __restrict__ x,
    const _Float16* __restrict__ W,
    const float* __restrict__ sb, const float* __restrict__ cb_,
    const float* __restrict__ g, const float* __restrict__ bt,
    const float* __restrict__ mn, const float* __restrict__ vr,
    _Float16* __restrict__ s1out, _Float16* __restrict__ c1out,
    const float* __restrict__ ew1, _Float16* __restrict__ ewp1,
    const float* __restrict__ ew2, _Float16* __restrict__ ewp2,
    const float* __restrict__ ew3, _Float16* __restrict__ ewp3){
  __shared__ __align__(16) _Float16 Ah[3*58*64];
  const int tid = threadIdx.x;
  const int b = blockIdx.x;

  if (b < 23040){
    if (b < 13824){
      wpackG_body<1152>((b % 4608)*256 + tid, b / 4608, ew1, 1024, ewp1);
    } else if (b < 19968){
      int t2 = b - 13824;
      wpackG_body<1024>((t2 % 2048)*256 + tid, t2 / 2048, ew2, 512, ewp2);
    } else {
      int t3 = b - 19968;
      wpackG_body<512>((t3 % 1024)*256 + tid, t3 / 1024, ew3, 512, ewp3);
    }
    return;
  }

  // XCD-aware bijective swizzle: 7168 = 8 * 896; XCD k gets images [32k,32k+32)
  const int lb = b - 23040;
  const int w = (lb & 7)*896 + (lb >> 3);
  const int n = w / 28, oh0 = (w % 28) * 2;

  if (tid < 48){
    int rr = tid >> 4, side = (tid >> 3) & 1, q = tid & 7;
    int col = side ? 57 : 0;
    *(int4*)((char*)Ah + (((rr*58 + col) << 7) + q*16)) = (int4){0,0,0,0};
  }

  {
    const int m = tid & 63;
    const bool mok = (m < 56);
    const int cc = m + 1;
    int rc0 = tid >> 6;
    int ic   = (rc0 == 3) ? 0 : rc0;
    int ridx = (rc0 == 3) ? 1 : 0;
    #pragma unroll
    for (int j = 0; j < 9; ++j){
      const int ih = 4*oh0 - 4 + ridx;
      if (mok){
        float4 v = {0.f,0.f,0.f,0.f};
        if (ih >= 0)
          v = *(const float4*)(x + ((size_t)(n*3 + ic)*224 + ih)*224 + 4*m);
        const int rr = ridx >> 2, pr = ridx & 3;
        int boff = (((rr*58 + cc) << 7) + ic*32 + pr*8) ^ ((cc & 7) << 4);
        _Float16 h4[4] = {(_Float16)v.x, (_Float16)v.y, (_Float16)v.z, (_Float16)v.w};
        *(unsigned long long*)((char*)Ah + boff) = *(unsigned long long*)h4;
      }
      ic += 1; ridx += 1;
      if (ic >= 3){ ic -= 3; ridx += 1; }
    }
  }
  __syncthreads();

  const int wid = tid >> 6, lane = tid & 63;
  const int kg8 = (lane >> 4) * 8;
  f32x4 acc[2][2];
  #pragma unroll
  for (int mi = 0; mi < 2; ++mi)
    #pragma unroll
    for (int nf = 0; nf < 2; ++nf) acc[mi][nf] = (f32x4){0.f,0.f,0.f,0.f};

  #pragma unroll
  for (int s = 0; s < 6; ++s){
    const int kk = s*32 + kg8;
    const int t = kk / 48, c0 = kk - t*48;
    const int ra = t >> 1, ca = t & 1;
    f16x8 ah[2];
    #pragma unroll
    for (int mi = 0; mi < 2; ++mi){
      const int m = 2*wid + mi;
      const int rowsel = m >> 2;
      const int ow = (m & 3)*16 + (lane & 15);
      const int owc = ow > 55 ? 55 : ow;
      const int col = owc + ca;
      const int bidx = ((((rowsel + ra)*58 + col) << 7) + c0*2) ^ ((col & 7) << 4);
      ah[mi] = *(const f16x8*)((const char*)Ah + bidx);
    }
    #pragma unroll
    for (int nf = 0; nf < 2; ++nf){
      const f16x8 bw = *(const f16x8*)(W + (s*2 + nf)*512 + lane*8);
      #pragma unroll
      for (int mi = 0; mi < 2; ++mi)
        acc[mi][nf] = __builtin_amdgcn_mfma_f32_16x16x32_f16(ah[mi], bw, acc[mi][nf], 0,0,0);
    }
  }

  const int oc = lane & 15;
  const float sbv = sb[oc];
  const float scv = g[oc] * __frsqrt_rn(vr[oc] + 1e-5f);
  const float mnv = mn[oc], btv = bt[oc], cbv = cb_[oc];
  #pragma unroll
  for (int mi = 0; mi < 2; ++mi){
    const int m = 2*wid + mi;
    const int row = oh0 + (m >> 2);
    const int owb = (m & 3)*16 + (lane >> 4)*4;
    #pragma unroll
    for (int r = 0; r < 4; ++r){
      const int ow = owb + r;
      if (ow >= 56) continue;
      float vs = acc[mi][0][r] + sbv;
      vs = fmaxf((vs - mnv)*scv + btv, 0.f);
      const size_t o = (((size_t)n*56 + row)*56 + ow)*16 + oc;
      s1out[o] = (_Float16)vs;
      c1out[o] = (_Float16)leakyf(acc[mi][1][r] + cbv);
    }
  }
}

// ---------------- strided (S=2) MFMA conv body ------------------------------
template<int OC,int K,int P,int IH,int IW,int ACT,bool OUT16,bool GATE,bool POOLIN>
DEV void convS_body(int bx, int tid, _Float16* A, float* gred,
    const _Float16* __restrict__ in,
    const _Float16* __restrict__ W,
    const float* __restrict__ bias,
    const float* __restrict__ bng, const float* __restrict__ bnb,
    const float* __restrict__ bnm, const float* __restrict__ bnv,
    float* __restrict__ outF, _Float16* __restrict__ outH,
    float* __restrict__ gsum){
  constexpr int F = OC/16, KWP = (K+1)/2;
  constexpr int RW = POOLIN ? (IW+1) : IW;

  const int n = bx / 28, oh = bx % 28;

  if (GATE && tid < 32) gred[tid] = 0.f;

  for (int i = tid; i < K*60*2; i += 256){
    int half = i & 1; int p = i >> 1;
    int c = p % 60; int r = p / 60;
    int ih = 2*oh - P + r, iw = c - P;
    int4 v = {0,0,0,0};
    if (ih >= 0 && ih < IH && iw >= 0 && iw < IW){
      const _Float16* q = in + (((size_t)n*(POOLIN ? IH+1 : IH) + ih)*RW + iw)*16 + half*8;
      if (POOLIN){
        f16x8 a = *(const f16x8*)q;
        f16x8 b = *(const f16x8*)(q + 16);
        f16x8 cc = *(const f16x8*)(q + RW*16);
        f16x8 d = *(const f16x8*)(q + RW*16 + 16);
        f16x8 mx = max8(max8(a, b), max8(cc, d));
        v = *(int4*)&mx;
      } else {
        v = *(const int4*)q;
      }
    }
    int byte = ((r*60 + c)*32 + half*16) ^ (((c>>1)&7) << 4);
    *(int4*)((char*)A + byte) = v;
  }
  __syncthreads();

  const int wid = tid >> 6, lane = tid & 63;
  const int fsel = wid & 1, mb = wid >> 1;
  const int ow_l = min(mb*16 + (lane & 15), 27);
  const int ic0b = ((lane >> 4) & 1) * 16;
  const int kwo  = (lane >> 4) >> 1;

  f32x4 acc = {0.f,0.f,0.f,0.f};
  #pragma unroll
  for (int kh = 0; kh < K; ++kh){
    #pragma unroll
    for (int kwp = 0; kwp < KWP; ++kwp){
      const int kw = 2*kwp + kwo;
      const int c = 2*ow_l + kw;
      int byte = ((kh*60 + c)*32 + ic0b) ^ (((c>>1)&7) << 4);
      f16x8 a = *(const f16x8*)((const char*)A + byte);
      const int s = kh*KWP + kwp;
      const f16x8 b = *(const f16x8*)(W + (s*F + fsel)*512 + lane*8);
      acc = __builtin_amdgcn_mfma_f32_16x16x32_f16(a, b, acc, 0,0,0);
    }
  }

  const int oc = fsel*16 + (lane & 15);
  float bv = bias[oc], sc = 1.f, mm = 0.f, bb = 0.f;
  if (ACT == 1){
    sc = bng[oc] * __frsqrt_rn(bnv[oc] + 1e-5f);
    mm = bnm[oc]; bb = bnb[oc];
  }
  float lsum = 0.f;
  #pragma unroll
  for (int r = 0; r < 4; ++r){
    const int ow = mb*16 + (lane >> 4)*4 + r;
    if (ow >= 28) continue;
    float v = acc[r] + bv;
    if (ACT == 1) v = fmaxf((v - mm)*sc + bb, 0.f);
    else          v = leakyf(v);
    if (GATE){
      lsum += v;
    } else {
      const size_t o = (((size_t)n*28 + oh)*28 + ow)*OC + oc;
      if (OUT16) outH[o] = (_Float16)v;
      else       outF[o] = v;
    }
  }
  if (GATE){
    atomicAdd(&gred[oc], lsum);
    __syncthreads();
    if (tid < 32) atomicAdd(&gsum[n*32 + tid], gred[tid]);
  }
}

// ------- merged scout2(GATE) + conv2(POOLIN): independent, co-resident ------
__global__ __launch_bounds__(256) void convSS_k(
    const _Float16* __restrict__ s1h, const _Float16* __restrict__ wps2,
    const float* __restrict__ sb2,
    const float* __restrict__ bn2g, const float* __restrict__ bn2b,
    const float* __restrict__ bn2m, const float* __restrict__ bn2v,
    float* __restrict__ gsum,
    const _Float16* __restrict__ c1h, const _Float16* __restrict__ wp2,
    const float* __restrict__ tb2, _Float16* __restrict__ c2h){
  __shared__ __align__(16) _Float16 A[5*60*16];
  __shared__ float gred[32];
  const int tid = threadIdx.x;
  if (blockIdx.x < BATCH*28){
    convS_body<32,3,1,56,56,1,false,true,false>(blockIdx.x, tid, A, gred,
        s1h, wps2, sb2, bn2g, bn2b, bn2m, bn2v, nullptr, nullptr, gsum);
  } else {
    convS_body<32,5,2,55,55,0,true,false,true>(blockIdx.x - BATCH*28, tid, A, gred,
        c1h, wp2, tb2, nullptr, nullptr, nullptr, nullptr, nullptr, c2h, nullptr);
  }
}

// ---------------- MFMA fp16 3x3 s1 p1 conv on 27x27, unpadded NHWC ----------
template<int IC,int OC,bool POOLIN>
__global__ __launch_bounds__(256) void convM_k(
    const _Float16* __restrict__ Ag,
    const _Float16* __restrict__ W,
    const float* __restrict__ bias,
    _Float16* __restrict__ Out)
{
  constexpr int S = IC/32, FTOT = OC/16, FW = FTOT/2;
  constexpr int ICB = IC*2, ICG = ICB/16;
  __shared__ __align__(16) char A[4*34*ICB];

  const int tid = threadIdx.x;
  const int bx = blockIdx.x;
  const int n = bx / 14, pr = bx % 14;
  const int oh0 = pr * 2;

  for (int g = tid; g < 4*34*ICG; g += 256){
    int r = g / (34*ICG);
    int rem = g - r*(34*ICG);
    int c = rem / ICG, q = rem - c*ICG;
    int ir = oh0 + r - 1, icol = c - 1;
    int4 v = {0,0,0,0};
    if (ir >= 0 && ir < 27 && icol >= 0 && icol < 27){
      if (POOLIN){
        const _Float16* p0 = Ag + (((size_t)n*28 + ir)*28 + icol)*IC + q*8;
        f16x8 a = *(const f16x8*)p0;
        f16x8 b = *(const f16x8*)(p0 + IC);
        f16x8 cc = *(const f16x8*)(p0 + 28*IC);
        f16x8 d = *(const f16x8*)(p0 + 28*IC + IC);
        f16x8 mx = max8(max8(a, b), max8(cc, d));
        v = *(int4*)&mx;
      } else {
        v = *(const int4*)(Ag + (((size_t)n*27 + ir)*27 + icol)*IC + q*8);
      }
    }
    int off = (r*34 + c)*ICB + q*16;
    int swz = off ^ ((c & 7) << 4);
    *(int4*)(A + swz) = v;
  }
  __syncthreads();

  const int wid = tid >> 6, lane = tid & 63;
  const int rsel = wid & 1, ocq = wid >> 1;
  const int c0 = lane & 15, kg = (lane >> 4) * 16;
  const int colb0 = c0*ICB + kg, colb1 = (16 + c0)*ICB + kg;
  int msk[3];
  #pragma unroll
  for (int kw = 0; kw < 3; ++kw) msk[kw] = ((c0 + kw) & 7) << 4;

  f32x4 acc[2][FW];
  #pragma unroll
  for (int m = 0; m < 2; ++m)
    #pragma unroll
    for (int f = 0; f < FW; ++f) acc[m][f] = (f32x4){0.f,0.f,0.f,0.f};

  #pragma unroll
  for (int kh = 0; kh < 3; ++kh){
    #pragma unroll
    for (int kw = 0; kw < 3; ++kw){
      #pragma unroll
      for (int s = 0; s < S; ++s){
        const int fr0 = (((kh*3 + kw)*S + s)*FTOT + ocq*FW) * 512 + lane*8;
        f16x8 b[FW];
        #pragma unroll
        for (int f = 0; f < FW; ++f)
          b[f] = *(const f16x8*)(W + fr0 + f*512);
        const int base = ((rsel + kh)*34 + kw)*ICB + s*64;
        const int o0 = (base + colb0) ^ msk[kw];
        const int o1 = (base + colb1) ^ msk[kw];
        f16x8 a0 = *(const f16x8*)(A + o0);
        f16x8 a1 = *(const f16x8*)(A + o1);
        #pragma unroll
        for (int f = 0; f < FW; ++f){
          acc[0][f] = __builtin_amdgcn_mfma_f32_16x16x32_f16(a0, b[f], acc[0][f], 0,0,0);
          acc[1][f] = __builtin_amdgcn_mfma_f32_16x16x32_f16(a1, b[f], acc[1][f], 0,0,0);
        }
      }
    }
  }

  const int orow = oh0 + rsel;
  if (orow >= 27) return;
  #pragma unroll
  for (int f = 0; f < FW; ++f){
    const int oc = (ocq*FW + f)*16 + c0;
    const float bv = bias[oc];
    #pragma unroll
    for (int m = 0; m < 2; ++m){
      #pragma unroll
      for (int r = 0; r < 4; ++r){
        const int ow = m*16 + (lane >> 4)*4 + r;
        if (ow >= 27) continue;
        float v = leakyf(acc[m][f][r] + bv);
        Out[(((size_t)n*27 + orow)*27 + ow)*OC + oc] = (_Float16)v;
      }
    }
  }
}

// ---------------- single-fp16 MFMA GEMM (head layers 1,2) -------------------
template<int KTOT,int ACT>
__global__ __launch_bounds__(256) void gemmH_k(
    const _Float16* __restrict__ A, long strideA,
    const _Float16* __restrict__ W,
    const float* __restrict__ bias, int N,
    _Float16* __restrict__ OutH){
  const int e = blockIdx.z;
  A += (size_t)e * strideA;
  const int NF = N >> 4, KT = KTOT >> 5;
  W += (size_t)e * NF * KT * 512;
  const float* bs = bias + (size_t)e * N;
  const size_t ob = (size_t)e * 256 * N;

  const int tid = threadIdx.x, wid = tid >> 6, lane = tid & 63;
  const int mblk = blockIdx.x * 32;
  const int nf = blockIdx.y * 4 + wid;
  const int r0 = mblk + (lane & 15);
  const int kof = (lane >> 4) * 8;

  f32x4 acc0 = {0,0,0,0}, acc1 = {0,0,0,0};
  for (int t = 0; t < KT; ++t){
    const int k = t*32 + kof;
    f16x8 a0 = *(const f16x8*)(A + (size_t)r0*KTOT + k);
    f16x8 a1 = *(const f16x8*)(A + (size_t)(r0+16)*KTOT + k);
    const f16x8 b = *(const f16x8*)(W + ((size_t)t*NF + nf)*512 + lane*8);
    acc0 = __builtin_amdgcn_mfma_f32_16x16x32_f16(a0, b, acc0, 0,0,0);
    acc1 = __builtin_amdgcn_mfma_f32_16x16x32_f16(a1, b, acc1, 0,0,0);
  }
  const int n = nf*16 + (lane & 15);
  const float bv = bs[n];
  #pragma unroll
  for (int mi = 0; mi < 2; ++mi){
    f32x4 a = mi ? acc1 : acc0;
    #pragma unroll
    for (int r = 0; r < 4; ++r){
      const int m = mblk + mi*16 + (lane >> 4)*4 + r;
      float v = a[r] + bv;
      if (ACT == 1) v = leakyf(v);
      OutH[ob + (size_t)m*N + n] = (_Float16)v;
    }
  }
}

// ------- head layer 3 + per-block gate + gated combine ----------------------
__global__ __launch_bounds__(256) void gemmC_k(
    const _Float16* __restrict__ A,      // h2 [3][256][512]
    const _Float16* __restrict__ W,      // ewp3 [3][32][16]*512
    const float* __restrict__ b3,        // eb3 [3][512]
    const float* __restrict__ gsum,      // [256][32]
    const float* __restrict__ cw, const float* __restrict__ cb,
    float* __restrict__ out){            // [256][512]
  __shared__ float combL[16][3];
  const int tid = threadIdx.x, wid = tid >> 6, lane = tid & 63;
  const int mblk = blockIdx.x * 16;

  if (tid < 16){
    const int n = mblk + tid;
    float mch[32];
    #pragma unroll
    for (int c = 0; c < 32; ++c) mch[c] = gsum[n*32 + c] / 784.f;
    float lg[3];
    #pragma unroll
    for (int e = 0; e < 3; ++e){
      float a = cb[e];
      #pragma unroll
      for (int c = 0; c < 32; ++c) a += mch[c] * cw[e*32 + c];
      lg[e] = a;
    }
    float m = fmaxf(lg[0], fmaxf(lg[1], lg[2]));
    float ex[3], sum = 0.f;
    #pragma unroll
    for (int e = 0; e < 3; ++e){ ex[e] = expf(lg[e] - m); sum += ex[e]; }
    float pr[3];
    #pragma unroll
    for (int e = 0; e < 3; ++e) pr[e] = ex[e] / sum;
    int i1 = 0;
    if (pr[1] > pr[0]) i1 = 1;
    if (pr[2] > pr[i1]) i1 = 2;
    int i2 = -1;
    for (int e = 0; e < 3; ++e){
      if (e == i1) continue;
      if (i2 < 0 || pr[e] > pr[i2]) i2 = e;
    }
    float s12 = pr[i1] + pr[i2] + 1e-6f;
    float cmb[3] = {0.f, 0.f, 0.f};
    cmb[i1] = pr[i1] / s12;
    cmb[i2] = pr[i2] / s12;
    combL[tid][0] = cmb[0];
    combL[tid][1] = cmb[1];
    combL[tid][2] = cmb[2];
  }
  __syncthreads();

  const int nf = blockIdx.y * 4 + wid;
  const int r0 = mblk + (lane & 15);
  const int kof = (lane >> 4) * 8;
  const int n = nf*16 + (lane & 15);

  f32x4 oacc = {0.f,0.f,0.f,0.f};
  #pragma unroll
  for (int e = 0; e < 3; ++e){
    const _Float16* Ae = A + (size_t)e * 256 * 512;
    const _Float16* We = W + (size_t)e * 32 * 16 * 512;
    f32x4 acc = {0.f,0.f,0.f,0.f};
    for (int t = 0; t < 16; ++t){
      f16x8 a = *(const f16x8*)(Ae + (size_t)r0*512 + t*32 + kof);
      const f16x8 b = *(const f16x8*)(We + ((size_t)t*32 + nf)*512 + lane*8);
      acc = __builtin_amdgcn_mfma_f32_16x16x32_f16(a, b, acc, 0,0,0);
    }
    const float bv = b3[e*512 + n];
    #pragma unroll
    for (int r = 0; r < 4; ++r){
      const int lr = (lane >> 4)*4 + r;
      oacc[r] += combL[lr][e] * (acc[r] + bv);
    }
  }
  #pragma unroll
  for (int r = 0; r < 4; ++r){
    const int m = mblk + (lane >> 4)*4 + r;
    out[(size_t)m*512 + n] = oacc[r];
  }
}

// ------ channel-parallel fused maxpool2s1(27->26) + adaptive avg(26->3) -----
__global__ __launch_bounds__(256) void papool2_k(const _Float16* __restrict__ in,
                                                 _Float16* __restrict__ flat16){
  __shared__ float red[2][128][9];
  const int n = blockIdx.x;
  const int tid = threadIdx.x;
  const int h = tid >> 7, c = tid & 127;
  const _Float16* p = in + (size_t)n * 729 * 128 + c;

  float sum[9];
  #pragma unroll
  for (int j = 0; j < 9; ++j) sum[j] = 0.f;

  float prev[27], cur[27];
  const int r0 = h * 13;
  #pragma unroll
  for (int rr = 0; rr < 14; ++rr){
    const int r = r0 + rr;
    #pragma unroll
    for (int cc = 0; cc < 27; ++cc)
      cur[cc] = (float)p[(size_t)(r*27 + cc) * 128];
    if (rr > 0){
      const int pr = r - 1;
      const bool b0 = (pr < 9), b1 = (pr >= 8) && (pr < 18), b2 = (pr >= 17);
      #pragma unroll
      for (int cc = 0; cc < 26; ++cc){
        float v = fmaxf(fmaxf(prev[cc], prev[cc+1]), fmaxf(cur[cc], cur[cc+1]));
        if (b0){
          if (cc < 9)             sum[0] += v;
          if (cc >= 8 && cc < 18) sum[1] += v;
          if (cc >= 17)           sum[2] += v;
        }
        if (b1){
          if (cc < 9)             sum[3] += v;
          if (cc >= 8 && cc < 18) sum[4] += v;
          if (cc >= 17)           sum[5] += v;
        }
        if (b2){
          if (cc < 9)             sum[6] += v;
          if (cc >= 8 && cc < 18) sum[7] += v;
          if (cc >= 17)           sum[8] += v;
        }
      }
    }
    #pragma unroll
    for (int cc = 0; cc < 27; ++cc) prev[cc] = cur[cc];
  }

  #pragma unroll
  for (int j = 0; j < 9; ++j) red[h][c][j] = sum[j];
  __syncthreads();

  if (tid < 128){
    const float rcp[9] = {1.f/81, 1.f/90, 1.f/81, 1.f/90, 1.f/100, 1.f/90,
                          1.f/81, 1.f/90, 1.f/81};
    _Float16* o = flat16 + (size_t)n * 1152 + tid * 9;
    #pragma unroll
    for (int j = 0; j < 9; ++j)
      o[j] = (_Float16)((red[0][tid][j] + red[1][tid][j]) * rcp[j]);
  }
}

// ============================================================================
extern "C" void kernel_launch(void* const* d_in, const int* in_sizes, int n_in,
                              void* d_out, int out_size, void* d_ws, size_t ws_size,
                              hipStream_t stream){
  const float* x    = (const float*)d_in[0];
  const float* tw1  = (const float*)d_in[1];  const float* tb1 = (const float*)d_in[2];
  const float* tw2  = (const float*)d_in[3];  const float* tb2 = (const float*)d_in[4];
  const float* tw3  = (const float*)d_in[5];  const float* tb3 = (const float*)d_in[6];
  const float* tw4  = (const float*)d_in[7];  const float* tb4 = (const float*)d_in[8];
  const float* sw1  = (const float*)d_in[9];  const float* sb1 = (const float*)d_in[10];
  const float* bn1g = (const float*)d_in[11]; const float* bn1b = (const float*)d_in[12];
  const float* bn1m = (const float*)d_in[13]; const float* bn1v = (const float*)d_in[14];
  const float* sw2  = (const float*)d_in[15]; const float* sb2 = (const float*)d_in[16];
  const float* bn2g = (const float*)d_in[17]; const float* bn2b = (const float*)d_in[18];
  const float* bn2m = (const float*)d_in[19]; const float* bn2v = (const float*)d_in[20];
  const float* cw   = (const float*)d_in[21]; const float* cb  = (const float*)d_in[22];
  const float* ew1  = (const float*)d_in[23]; const float* eb1 = (const float*)d_in[24];
  const float* ew2  = (const float*)d_in[25]; const float* eb2 = (const float*)d_in[26];
  const float* ew3  = (const float*)d_in[27]; const float* eb3 = (const float*)d_in[28];
  float* out = (float*)d_out;

  // ---- workspace layout (floats), ~157 MB ----
  float* ws = (float*)d_ws;
  size_t off = 0;
  _Float16* flat16 = (_Float16*)(ws + off); off += 147456;
  float* gsum   = ws + off; off += BATCH * 32;
  _Float16* wpk3 = (_Float16*)(ws + off); off += 9216;
  _Float16* wpk4 = (_Float16*)(ws + off); off += 36864;
  _Float16* wp2  = (_Float16*)(ws + off); off += 7680;
  _Float16* wps2 = (_Float16*)(ws + off); off += 3072;
  _Float16* wpf  = (_Float16*)(ws + off); off += 3072;
  off += 16;                                                      // guard pad
  float* bufA   = ws + off; off += 13778944;
  off += 16;                                                      // guard pad
  float* bufB   = ws + off; off += 23887872;
  off += 16;
  (void)ws_size; (void)in_sizes; (void)n_in; (void)out_size;

  // bufA aliases: s1h [0, 6,422,528 floats) ; C3u later ; expert packs parked
  // at float offset 6,500,000 (disjoint from both)
  _Float16* s1h = (_Float16*)bufA;
  _Float16* C3u = (_Float16*)bufA;
  _Float16* ewp1 = (_Float16*)(bufA + 6500000);
  _Float16* ewp2 = ewp1 + 3538944;
  _Float16* ewp3 = ewp2 + 1572864;
  // bufB aliases
  _Float16* c1h = (_Float16*)bufB;
  _Float16* c2h = (_Float16*)(bufB + 14000000);
  _Float16* c4h = (_Float16*)bufB;
  _Float16* h1  = (_Float16*)bufB;
  _Float16* h2  = h1 + 786432;

  dim3 blk(256);

  // ---- conv weight packs + gsum zero (one small kernel) ----
  wpackC_k<<<dim3(500), blk, 0, stream>>>(
      tw3, wpk3, tw4, wpk4, tw2, wp2, sw2, wps2, sw1, tw1, wpf, gsum);

  // ---- expert packs (first) + fused scout1+conv1 (XCD-swizzled) ----
  fusedX_k<<<dim3(30208), blk, 0, stream>>>(
      x, wpf, sb1, tb1, bn1g, bn1b, bn1m, bn1v, s1h, c1h,
      ew1, ewp1, ew2, ewp2, ew3, ewp3);

  // ---- merged scout2(gate-sum) + conv2(fused pool1) ----
  convSS_k<<<dim3(BATCH*28*2), blk, 0, stream>>>(
      s1h, wps2, sb2, bn2g, bn2b, bn2m, bn2v, gsum,
      c1h, wp2, tb2, c2h);

  // ---- conv3 with fused pool2 -> unpadded C3u ----
  convM_k<32,64,true><<<dim3(BATCH*14), blk, 0, stream>>>(
      c2h, wpk3, tb3, C3u);

  // ---- conv4 (unpadded input, predicated staging) -> fp16 c4h ----
  convM_k<64,128,false><<<dim3(BATCH*14), blk, 0, stream>>>(
      C3u, wpk4, tb4, c4h);

  // ---- pool+adaptive-avg -> fp16 flat ----
  papool2_k<<<dim3(BATCH), blk, 0, stream>>>(c4h, flat16);

  // ---- MoE head GEMMs (layer 3 fused with gate + combine) ----
  gemmH_k<1152,1><<<dim3(8,16,3), blk, 0, stream>>>(
      flat16, 0L, ewp1, eb1, 1024, h1);
  gemmH_k<1024,1><<<dim3(8,8,3), blk, 0, stream>>>(
      h1, 256L*1024, ewp2, eb2, 512, h2);
  gemmC_k<<<dim3(16,8), blk, 0, stream>>>(
      h2, ewp3, eb3, gsum, cw, cb, out);
}

// Round 24
// 244.120 us; speedup vs baseline: 1.2439x; 1.0112x over previous
//
#include <hip/hip_runtime.h>

#define DEV static __device__ __forceinline__

constexpr int BATCH = 256;

DEV float leakyf(float x){ return x > 0.f ? x : 0.2f * x; }

typedef _Float16 f16x8 __attribute__((ext_vector_type(8)));
typedef float f32x4 __attribute__((ext_vector_type(4)));

DEV f16x8 max8(f16x8 a, f16x8 b){
  f16x8 r;
  #pragma unroll
  for (int j = 0; j < 8; ++j) r[j] = a[j] > b[j] ? a[j] : b[j];
  return r;
}

// ---------------- weight-pack bodies ----------------------------------------
template<int IC,int OC>
DEV void wpackM_body(int i, const float* __restrict__ w, _Float16* __restrict__ wp){
  constexpr int F = OC/16;
  int j = i & 7, L = (i >> 3) & 63, rest = i >> 9;
  int f = rest % F; int q2 = rest / F; int s = q2 % (IC/32); int t = q2 / (IC/32);
  int oc = f*16 + (L & 15), ic = s*32 + (L >> 4)*8 + j;
  wp[i] = (_Float16)w[((size_t)oc*IC + ic)*9 + t];
}

template<int OC,int K>
DEV void wpackS_body(int i, const float* __restrict__ w, _Float16* __restrict__ wp){
  constexpr int F = OC/16, KWP = (K+1)/2;
  int j = i & 7, L = (i >> 3) & 63, rest = i >> 9;
  int f = rest % F, s = rest / F;
  int kh = s / KWP, kwp = s % KWP;
  int k = (L >> 4)*8 + j;
  int kw = 2*kwp + (k >> 4), ic = k & 15;
  int oc = f*16 + (L & 15);
  float v = (kw < K) ? w[((size_t)(oc*16 + ic)*K + kh)*K + kw] : 0.f;
  wp[i] = (_Float16)v;
}

DEV void wpackF_body(int i, const float* __restrict__ sw1,
                     const float* __restrict__ tw1, _Float16* __restrict__ wp){
  int j = i & 7, L = (i >> 3) & 63, rest = i >> 9;
  int nf = rest & 1, s = rest >> 1;
  int k = s*32 + (L >> 4)*8 + j;
  int oc = L & 15;
  int t = k / 48, c = k % 48;
  int dr = (t >> 1) - 1, dc = (t & 1) - 1;
  int ic = c >> 4, pr = (c >> 2) & 3, pc = c & 3;
  float v = 0.f;
  if (nf == 0){
    int kh = 4*dr + pr + 3, kw = 4*dc + pc + 3;
    if (kh >= 0 && kh < 7 && kw >= 0 && kw < 7) v = sw1[((oc*3 + ic)*7 + kh)*7 + kw];
  } else {
    int kh = 4*dr + pr + 1, kw = 4*dc + pc + 1;
    if (kh >= 0 && kh < 3 && kw >= 0 && kw < 3) v = tw1[((oc*3 + ic)*3 + kh)*3 + kw];
  }
  wp[i] = (_Float16)v;
}

template<int KTOT>
DEV void wpackG_body(int i, int e, const float* __restrict__ w, int N,
                     _Float16* __restrict__ wp){
  const int NF = N >> 4;
  const int total = NF * (KTOT >> 5) * 512;
  w  += (size_t)e * N * KTOT;
  wp += (size_t)e * total;
  int j = i & 7, L = (i >> 3) & 63, rest = i >> 9;
  int nf = rest % NF, t = rest / NF;
  int n = nf*16 + (L & 15), k = t*32 + (L >> 4)*8 + j;
  wp[i] = (_Float16)w[(size_t)n*KTOT + k];
}

// ------- conv weight packs + gsum zero, one small kernel --------------------
__global__ __launch_bounds__(256) void wpackC_k(
    const float* __restrict__ tw3, _Float16* __restrict__ wpk3,
    const float* __restrict__ tw4, _Float16* __restrict__ wpk4,
    const float* __restrict__ tw2, _Float16* __restrict__ wp2,
    const float* __restrict__ sw2, _Float16* __restrict__ wps2,
    const float* __restrict__ sw1, const float* __restrict__ tw1,
    _Float16* __restrict__ wpf, float* __restrict__ gsum){
  const int b = blockIdx.x;
  const int tid = threadIdx.x;
  if (b < 72){
    wpackM_body<32,64>(b*256 + tid, tw3, wpk3);
  } else if (b < 360){
    wpackM_body<64,128>((b-72)*256 + tid, tw4, wpk4);
  } else if (b < 420){
    wpackS_body<32,5>((b-360)*256 + tid, tw2, wp2);
  } else if (b < 444){
    wpackS_body<32,3>((b-420)*256 + tid, sw2, wps2);
  } else if (b < 468){
    wpackF_body((b-444)*256 + tid, sw1, tw1, wpf);
  } else {
    gsum[(b-468)*256 + tid] = 0.f;
  }
}

// ---------- merged expert packs (first) + fused scout1+conv1 MFMA -----------
// Staging uses issue-early/write-late: all 9 float4 loads in flight before
// any cvt/ds_write (T14). vv[] statically indexed (full unroll).
__global__ __launch_bounds__(256) void fusedX_k(
    const float* __restrict__ x,
    const _Float16* __restrict__ W,
    const float* __restrict__ sb, const float* __restrict__ cb_,
    const float* __restrict__ g, const float* __restrict__ bt,
    const float* __restrict__ mn, const float* __restrict__ vr,
    _Float16* __restrict__ s1out, _Float16* __restrict__ c1out,
    const float* __restrict__ ew1, _Float16* __restrict__ ewp1,
    const float* __restrict__ ew2, _Float16* __restrict__ ewp2,
    const float* __restrict__ ew3, _Float16* __restrict__ ewp3){
  __shared__ __align__(16) _Float16 Ah[3*58*64];
  const int tid = threadIdx.x;
  const int b = blockIdx.x;

  if (b < 23040){
    if (b < 13824){
      wpackG_body<1152>((b % 4608)*256 + tid, b / 4608, ew1, 1024, ewp1);
    } else if (b < 19968){
      int t2 = b - 13824;
      wpackG_body<1024>((t2 % 2048)*256 + tid, t2 / 2048, ew2, 512, ewp2);
    } else {
      int t3 = b - 19968;
      wpackG_body<512>((t3 % 1024)*256 + tid, t3 / 1024, ew3, 512, ewp3);
    }
    return;
  }

  // XCD-aware bijective swizzle: 7168 = 8 * 896
  const int lb = b - 23040;
  const int w = (lb & 7)*896 + (lb >> 3);
  const int n = w / 28, oh0 = (w % 28) * 2;

  if (tid < 48){
    int rr = tid >> 4, side = (tid >> 3) & 1, q = tid & 7;
    int col = side ? 57 : 0;
    *(int4*)((char*)Ah + (((rr*58 + col) << 7) + q*16)) = (int4){0,0,0,0};
  }

  {
    const int m = tid & 63;
    const bool mok = (m < 56);
    const int cc = m + 1;
    const int rc0 = tid >> 6;

    float4 vv[9];
    { // pass 1: issue all loads (kept in flight; static vv indexing)
      int ic   = (rc0 == 3) ? 0 : rc0;
      int ridx = (rc0 == 3) ? 1 : 0;
      #pragma unroll
      for (int j = 0; j < 9; ++j){
        const int ih = 4*oh0 - 4 + ridx;
        float4 v = {0.f,0.f,0.f,0.f};
        if (mok && ih >= 0)
          v = *(const float4*)(x + ((size_t)(n*3 + ic)*224 + ih)*224 + 4*m);
        vv[j] = v;
        ic += 1; ridx += 1;
        if (ic >= 3){ ic -= 3; ridx += 1; }
      }
    }
    if (mok){ // pass 2: cvt + LDS writes
      int ic   = (rc0 == 3) ? 0 : rc0;
      int ridx = (rc0 == 3) ? 1 : 0;
      #pragma unroll
      for (int j = 0; j < 9; ++j){
        const int rr = ridx >> 2, pr = ridx & 3;
        int boff = (((rr*58 + cc) << 7) + ic*32 + pr*8) ^ ((cc & 7) << 4);
        _Float16 h4[4] = {(_Float16)vv[j].x, (_Float16)vv[j].y,
                          (_Float16)vv[j].z, (_Float16)vv[j].w};
        *(unsigned long long*)((char*)Ah + boff) = *(unsigned long long*)h4;
        ic += 1; ridx += 1;
        if (ic >= 3){ ic -= 3; ridx += 1; }
      }
    }
  }
  __syncthreads();

  const int wid = tid >> 6, lane = tid & 63;
  const int kg8 = (lane >> 4) * 8;
  f32x4 acc[2][2];
  #pragma unroll
  for (int mi = 0; mi < 2; ++mi)
    #pragma unroll
    for (int nf = 0; nf < 2; ++nf) acc[mi][nf] = (f32x4){0.f,0.f,0.f,0.f};

  #pragma unroll
  for (int s = 0; s < 6; ++s){
    const int kk = s*32 + kg8;
    const int t = kk / 48, c0 = kk - t*48;
    const int ra = t >> 1, ca = t & 1;
    f16x8 ah[2];
    #pragma unroll
    for (int mi = 0; mi < 2; ++mi){
      const int m = 2*wid + mi;
      const int rowsel = m >> 2;
      const int ow = (m & 3)*16 + (lane & 15);
      const int owc = ow > 55 ? 55 : ow;
      const int col = owc + ca;
      const int bidx = ((((rowsel + ra)*58 + col) << 7) + c0*2) ^ ((col & 7) << 4);
      ah[mi] = *(const f16x8*)((const char*)Ah + bidx);
    }
    #pragma unroll
    for (int nf = 0; nf < 2; ++nf){
      const f16x8 bw = *(const f16x8*)(W + (s*2 + nf)*512 + lane*8);
      #pragma unroll
      for (int mi = 0; mi < 2; ++mi)
        acc[mi][nf] = __builtin_amdgcn_mfma_f32_16x16x32_f16(ah[mi], bw, acc[mi][nf], 0,0,0);
    }
  }

  const int oc = lane & 15;
  const float sbv = sb[oc];
  const float scv = g[oc] * __frsqrt_rn(vr[oc] + 1e-5f);
  const float mnv = mn[oc], btv = bt[oc], cbv = cb_[oc];
  #pragma unroll
  for (int mi = 0; mi < 2; ++mi){
    const int m = 2*wid + mi;
    const int row = oh0 + (m >> 2);
    const int owb = (m & 3)*16 + (lane >> 4)*4;
    #pragma unroll
    for (int r = 0; r < 4; ++r){
      const int ow = owb + r;
      if (ow >= 56) continue;
      float vs = acc[mi][0][r] + sbv;
      vs = fmaxf((vs - mnv)*scv + btv, 0.f);
      const size_t o = (((size_t)n*56 + row)*56 + ow)*16 + oc;
      s1out[o] = (_Float16)vs;
      c1out[o] = (_Float16)leakyf(acc[mi][1][r] + cbv);
    }
  }
}

// ---------------- strided (S=2) MFMA conv body ------------------------------
template<int OC,int K,int P,int IH,int IW,int ACT,bool OUT16,bool GATE,bool POOLIN>
DEV void convS_body(int bx, int tid, _Float16* A, float* gred,
    const _Float16* __restrict__ in,
    const _Float16* __restrict__ W,
    const float* __restrict__ bias,
    const float* __restrict__ bng, const float* __restrict__ bnb,
    const float* __restrict__ bnm, const float* __restrict__ bnv,
    float* __restrict__ outF, _Float16* __restrict__ outH,
    float* __restrict__ gsum){
  constexpr int F = OC/16, KWP = (K+1)/2;
  constexpr int RW = POOLIN ? (IW+1) : IW;

  const int n = bx / 28, oh = bx % 28;

  if (GATE && tid < 32) gred[tid] = 0.f;

  for (int i = tid; i < K*60*2; i += 256){
    int half = i & 1; int p = i >> 1;
    int c = p % 60; int r = p / 60;
    int ih = 2*oh - P + r, iw = c - P;
    int4 v = {0,0,0,0};
    if (ih >= 0 && ih < IH && iw >= 0 && iw < IW){
      const _Float16* q = in + (((size_t)n*(POOLIN ? IH+1 : IH) + ih)*RW + iw)*16 + half*8;
      if (POOLIN){
        f16x8 a = *(const f16x8*)q;
        f16x8 b = *(const f16x8*)(q + 16);
        f16x8 cc = *(const f16x8*)(q + RW*16);
        f16x8 d = *(const f16x8*)(q + RW*16 + 16);
        f16x8 mx = max8(max8(a, b), max8(cc, d));
        v = *(int4*)&mx;
      } else {
        v = *(const int4*)q;
      }
    }
    int byte = ((r*60 + c)*32 + half*16) ^ (((c>>1)&7) << 4);
    *(int4*)((char*)A + byte) = v;
  }
  __syncthreads();

  const int wid = tid >> 6, lane = tid & 63;
  const int fsel = wid & 1, mb = wid >> 1;
  const int ow_l = min(mb*16 + (lane & 15), 27);
  const int ic0b = ((lane >> 4) & 1) * 16;
  const int kwo  = (lane >> 4) >> 1;

  f32x4 acc = {0.f,0.f,0.f,0.f};
  #pragma unroll
  for (int kh = 0; kh < K; ++kh){
    #pragma unroll
    for (int kwp = 0; kwp < KWP; ++kwp){
      const int kw = 2*kwp + kwo;
      const int c = 2*ow_l + kw;
      int byte = ((kh*60 + c)*32 + ic0b) ^ (((c>>1)&7) << 4);
      f16x8 a = *(const f16x8*)((const char*)A + byte);
      const int s = kh*KWP + kwp;
      const f16x8 b = *(const f16x8*)(W + (s*F + fsel)*512 + lane*8);
      acc = __builtin_amdgcn_mfma_f32_16x16x32_f16(a, b, acc, 0,0,0);
    }
  }

  const int oc = fsel*16 + (lane & 15);
  float bv = bias[oc], sc = 1.f, mm = 0.f, bb = 0.f;
  if (ACT == 1){
    sc = bng[oc] * __frsqrt_rn(bnv[oc] + 1e-5f);
    mm = bnm[oc]; bb = bnb[oc];
  }
  float lsum = 0.f;
  #pragma unroll
  for (int r = 0; r < 4; ++r){
    const int ow = mb*16 + (lane >> 4)*4 + r;
    if (ow >= 28) continue;
    float v = acc[r] + bv;
    if (ACT == 1) v = fmaxf((v - mm)*sc + bb, 0.f);
    else          v = leakyf(v);
    if (GATE){
      lsum += v;
    } else {
      const size_t o = (((size_t)n*28 + oh)*28 + ow)*OC + oc;
      if (OUT16) outH[o] = (_Float16)v;
      else       outF[o] = v;
    }
  }
  if (GATE){
    atomicAdd(&gred[oc], lsum);
    __syncthreads();
    if (tid < 32) atomicAdd(&gsum[n*32 + tid], gred[tid]);
  }
}

// ------- merged scout2(GATE) + conv2(POOLIN) --------------------------------
__global__ __launch_bounds__(256) void convSS_k(
    const _Float16* __restrict__ s1h, const _Float16* __restrict__ wps2,
    const float* __restrict__ sb2,
    const float* __restrict__ bn2g, const float* __restrict__ bn2b,
    const float* __restrict__ bn2m, const float* __restrict__ bn2v,
    float* __restrict__ gsum,
    const _Float16* __restrict__ c1h, const _Float16* __restrict__ wp2,
    const float* __restrict__ tb2, _Float16* __restrict__ c2h){
  __shared__ __align__(16) _Float16 A[5*60*16];
  __shared__ float gred[32];
  const int tid = threadIdx.x;
  if (blockIdx.x < BATCH*28){
    convS_body<32,3,1,56,56,1,false,true,false>(blockIdx.x, tid, A, gred,
        s1h, wps2, sb2, bn2g, bn2b, bn2m, bn2v, nullptr, nullptr, gsum);
  } else {
    convS_body<32,5,2,55,55,0,true,false,true>(blockIdx.x - BATCH*28, tid, A, gred,
        c1h, wp2, tb2, nullptr, nullptr, nullptr, nullptr, nullptr, c2h, nullptr);
  }
}

// ---------------- MFMA fp16 3x3 s1 p1 conv on 27x27, unpadded NHWC ----------
template<int IC,int OC,bool POOLIN>
__global__ __launch_bounds__(256) void convM_k(
    const _Float16* __restrict__ Ag,
    const _Float16* __restrict__ W,
    const float* __restrict__ bias,
    _Float16* __restrict__ Out)
{
  constexpr int S = IC/32, FTOT = OC/16, FW = FTOT/2;
  constexpr int ICB = IC*2, ICG = ICB/16;
  __shared__ __align__(16) char A[4*34*ICB];

  const int tid = threadIdx.x;
  const int bx = blockIdx.x;
  const int n = bx / 14, pr = bx % 14;
  const int oh0 = pr * 2;

  for (int g = tid; g < 4*34*ICG; g += 256){
    int r = g / (34*ICG);
    int rem = g - r*(34*ICG);
    int c = rem / ICG, q = rem - c*ICG;
    int ir = oh0 + r - 1, icol = c - 1;
    int4 v = {0,0,0,0};
    if (ir >= 0 && ir < 27 && icol >= 0 && icol < 27){
      if (POOLIN){
        const _Float16* p0 = Ag + (((size_t)n*28 + ir)*28 + icol)*IC + q*8;
        f16x8 a = *(const f16x8*)p0;
        f16x8 b = *(const f16x8*)(p0 + IC);
        f16x8 cc = *(const f16x8*)(p0 + 28*IC);
        f16x8 d = *(const f16x8*)(p0 + 28*IC + IC);
        f16x8 mx = max8(max8(a, b), max8(cc, d));
        v = *(int4*)&mx;
      } else {
        v = *(const int4*)(Ag + (((size_t)n*27 + ir)*27 + icol)*IC + q*8);
      }
    }
    int off = (r*34 + c)*ICB + q*16;
    int swz = off ^ ((c & 7) << 4);
    *(int4*)(A + swz) = v;
  }
  __syncthreads();

  const int wid = tid >> 6, lane = tid & 63;
  const int rsel = wid & 1, ocq = wid >> 1;
  const int c0 = lane & 15, kg = (lane >> 4) * 16;
  const int colb0 = c0*ICB + kg, colb1 = (16 + c0)*ICB + kg;
  int msk[3];
  #pragma unroll
  for (int kw = 0; kw < 3; ++kw) msk[kw] = ((c0 + kw) & 7) << 4;

  f32x4 acc[2][FW];
  #pragma unroll
  for (int m = 0; m < 2; ++m)
    #pragma unroll
    for (int f = 0; f < FW; ++f) acc[m][f] = (f32x4){0.f,0.f,0.f,0.f};

  #pragma unroll
  for (int kh = 0; kh < 3; ++kh){
    #pragma unroll
    for (int kw = 0; kw < 3; ++kw){
      #pragma unroll
      for (int s = 0; s < S; ++s){
        const int fr0 = (((kh*3 + kw)*S + s)*FTOT + ocq*FW) * 512 + lane*8;
        f16x8 b[FW];
        #pragma unroll
        for (int f = 0; f < FW; ++f)
          b[f] = *(const f16x8*)(W + fr0 + f*512);
        const int base = ((rsel + kh)*34 + kw)*ICB + s*64;
        const int o0 = (base + colb0) ^ msk[kw];
        const int o1 = (base + colb1) ^ msk[kw];
        f16x8 a0 = *(const f16x8*)(A + o0);
        f16x8 a1 = *(const f16x8*)(A + o1);
        #pragma unroll
        for (int f = 0; f < FW; ++f){
          acc[0][f] = __builtin_amdgcn_mfma_f32_16x16x32_f16(a0, b[f], acc[0][f], 0,0,0);
          acc[1][f] = __builtin_amdgcn_mfma_f32_16x16x32_f16(a1, b[f], acc[1][f], 0,0,0);
        }
      }
    }
  }

  const int orow = oh0 + rsel;
  if (orow >= 27) return;
  #pragma unroll
  for (int f = 0; f < FW; ++f){
    const int oc = (ocq*FW + f)*16 + c0;
    const float bv = bias[oc];
    #pragma unroll
    for (int m = 0; m < 2; ++m){
      #pragma unroll
      for (int r = 0; r < 4; ++r){
        const int ow = m*16 + (lane >> 4)*4 + r;
        if (ow >= 27) continue;
        float v = leakyf(acc[m][f][r] + bv);
        Out[(((size_t)n*27 + orow)*27 + ow)*OC + oc] = (_Float16)v;
      }
    }
  }
}

// ---------------- single-fp16 MFMA GEMM (head layers 1,2) -------------------
template<int KTOT,int ACT>
__global__ __launch_bounds__(256) void gemmH_k(
    const _Float16* __restrict__ A, long strideA,
    const _Float16* __restrict__ W,
    const float* __restrict__ bias, int N,
    _Float16* __restrict__ OutH){
  const int e = blockIdx.z;
  A += (size_t)e * strideA;
  const int NF = N >> 4, KT = KTOT >> 5;
  W += (size_t)e * NF * KT * 512;
  const float* bs = bias + (size_t)e * N;
  const size_t ob = (size_t)e * 256 * N;

  const int tid = threadIdx.x, wid = tid >> 6, lane = tid & 63;
  const int mblk = blockIdx.x * 32;
  const int nf = blockIdx.y * 4 + wid;
  const int r0 = mblk + (lane & 15);
  const int kof = (lane >> 4) * 8;

  f32x4 acc0 = {0,0,0,0}, acc1 = {0,0,0,0};
  for (int t = 0; t < KT; ++t){
    const int k = t*32 + kof;
    f16x8 a0 = *(const f16x8*)(A + (size_t)r0*KTOT + k);
    f16x8 a1 = *(const f16x8*)(A + (size_t)(r0+16)*KTOT + k);
    const f16x8 b = *(const f16x8*)(W + ((size_t)t*NF + nf)*512 + lane*8);
    acc0 = __builtin_amdgcn_mfma_f32_16x16x32_f16(a0, b, acc0, 0,0,0);
    acc1 = __builtin_amdgcn_mfma_f32_16x16x32_f16(a1, b, acc1, 0,0,0);
  }
  const int n = nf*16 + (lane & 15);
  const float bv = bs[n];
  #pragma unroll
  for (int mi = 0; mi < 2; ++mi){
    f32x4 a = mi ? acc1 : acc0;
    #pragma unroll
    for (int r = 0; r < 4; ++r){
      const int m = mblk + mi*16 + (lane >> 4)*4 + r;
      float v = a[r] + bv;
      if (ACT == 1) v = leakyf(v);
      OutH[ob + (size_t)m*N + n] = (_Float16)v;
    }
  }
}

// ------- head layer 3 + per-block gate + gated combine ----------------------
__global__ __launch_bounds__(256) void gemmC_k(
    const _Float16* __restrict__ A,
    const _Float16* __restrict__ W,
    const float* __restrict__ b3,
    const float* __restrict__ gsum,
    const float* __restrict__ cw, const float* __restrict__ cb,
    float* __restrict__ out){
  __shared__ float combL[16][3];
  const int tid = threadIdx.x, wid = tid >> 6, lane = tid & 63;
  const int mblk = blockIdx.x * 16;

  if (tid < 16){
    const int n = mblk + tid;
    float mch[32];
    #pragma unroll
    for (int c = 0; c < 32; ++c) mch[c] = gsum[n*32 + c] / 784.f;
    float lg[3];
    #pragma unroll
    for (int e = 0; e < 3; ++e){
      float a = cb[e];
      #pragma unroll
      for (int c = 0; c < 32; ++c) a += mch[c] * cw[e*32 + c];
      lg[e] = a;
    }
    float m = fmaxf(lg[0], fmaxf(lg[1], lg[2]));
    float ex[3], sum = 0.f;
    #pragma unroll
    for (int e = 0; e < 3; ++e){ ex[e] = expf(lg[e] - m); sum += ex[e]; }
    float pr[3];
    #pragma unroll
    for (int e = 0; e < 3; ++e) pr[e] = ex[e] / sum;
    int i1 = 0;
    if (pr[1] > pr[0]) i1 = 1;
    if (pr[2] > pr[i1]) i1 = 2;
    int i2 = -1;
    for (int e = 0; e < 3; ++e){
      if (e == i1) continue;
      if (i2 < 0 || pr[e] > pr[i2]) i2 = e;
    }
    float s12 = pr[i1] + pr[i2] + 1e-6f;
    float cmb[3] = {0.f, 0.f, 0.f};
    cmb[i1] = pr[i1] / s12;
    cmb[i2] = pr[i2] / s12;
    combL[tid][0] = cmb[0];
    combL[tid][1] = cmb[1];
    combL[tid][2] = cmb[2];
  }
  __syncthreads();

  const int nf = blockIdx.y * 4 + wid;
  const int r0 = mblk + (lane & 15);
  const int kof = (lane >> 4) * 8;
  const int n = nf*16 + (lane & 15);

  f32x4 oacc = {0.f,0.f,0.f,0.f};
  #pragma unroll
  for (int e = 0; e < 3; ++e){
    const _Float16* Ae = A + (size_t)e * 256 * 512;
    const _Float16* We = W + (size_t)e * 32 * 16 * 512;
    f32x4 acc = {0.f,0.f,0.f,0.f};
    for (int t = 0; t < 16; ++t){
      f16x8 a = *(const f16x8*)(Ae + (size_t)r0*512 + t*32 + kof);
      const f16x8 b = *(const f16x8*)(We + ((size_t)t*32 + nf)*512 + lane*8);
      acc = __builtin_amdgcn_mfma_f32_16x16x32_f16(a, b, acc, 0,0,0);
    }
    const float bv = b3[e*512 + n];
    #pragma unroll
    for (int r = 0; r < 4; ++r){
      const int lr = (lane >> 4)*4 + r;
      oacc[r] += combL[lr][e] * (acc[r] + bv);
    }
  }
  #pragma unroll
  for (int r = 0; r < 4; ++r){
    const int m = mblk + (lane >> 4)*4 + r;
    out[(size_t)m*512 + n] = oacc[r];
  }
}

// ------ channel-parallel fused maxpool2s1(27->26) + adaptive avg(26->3) -----
__global__ __launch_bounds__(256) void papool2_k(const _Float16* __restrict__ in,
                                                 _Float16* __restrict__ flat16){
  __shared__ float red[2][128][9];
  const int n = blockIdx.x;
  const int tid = threadIdx.x;
  const int h = tid >> 7, c = tid & 127;
  const _Float16* p = in + (size_t)n * 729 * 128 + c;

  float sum[9];
  #pragma unroll
  for (int j = 0; j < 9; ++j) sum[j] = 0.f;

  float prev[27], cur[27];
  const int r0 = h * 13;
  #pragma unroll
  for (int rr = 0; rr < 14; ++rr){
    const int r = r0 + rr;
    #pragma unroll
    for (int cc = 0; cc < 27; ++cc)
      cur[cc] = (float)p[(size_t)(r*27 + cc) * 128];
    if (rr > 0){
      const int pr = r - 1;
      const bool b0 = (pr < 9), b1 = (pr >= 8) && (pr < 18), b2 = (pr >= 17);
      #pragma unroll
      for (int cc = 0; cc < 26; ++cc){
        float v = fmaxf(fmaxf(prev[cc], prev[cc+1]), fmaxf(cur[cc], cur[cc+1]));
        if (b0){
          if (cc < 9)             sum[0] += v;
          if (cc >= 8 && cc < 18) sum[1] += v;
          if (cc >= 17)           sum[2] += v;
        }
        if (b1){
          if (cc < 9)             sum[3] += v;
          if (cc >= 8 && cc < 18) sum[4] += v;
          if (cc >= 17)           sum[5] += v;
        }
        if (b2){
          if (cc < 9)             sum[6] += v;
          if (cc >= 8 && cc < 18) sum[7] += v;
          if (cc >= 17)           sum[8] += v;
        }
      }
    }
    #pragma unroll
    for (int cc = 0; cc < 27; ++cc) prev[cc] = cur[cc];
  }

  #pragma unroll
  for (int j = 0; j < 9; ++j) red[h][c][j] = sum[j];
  __syncthreads();

  if (tid < 128){
    const float rcp[9] = {1.f/81, 1.f/90, 1.f/81, 1.f/90, 1.f/100, 1.f/90,
                          1.f/81, 1.f/90, 1.f/81};
    _Float16* o = flat16 + (size_t)n * 1152 + tid * 9;
    #pragma unroll
    for (int j = 0; j < 9; ++j)
      o[j] = (_Float16)((red[0][tid][j] + red[1][tid][j]) * rcp[j]);
  }
}

// ============================================================================
extern "C" void kernel_launch(void* const* d_in, const int* in_sizes, int n_in,
                              void* d_out, int out_size, void* d_ws, size_t ws_size,
                              hipStream_t stream){
  const float* x    = (const float*)d_in[0];
  const float* tw1  = (const float*)d_in[1];  const float* tb1 = (const float*)d_in[2];
  const float* tw2  = (const float*)d_in[3];  const float* tb2 = (const float*)d_in[4];
  const float* tw3  = (const float*)d_in[5];  const float* tb3 = (const float*)d_in[6];
  const float* tw4  = (const float*)d_in[7];  const float* tb4 = (const float*)d_in[8];
  const float* sw1  = (const float*)d_in[9];  const float* sb1 = (const float*)d_in[10];
  const float* bn1g = (const float*)d_in[11]; const float* bn1b = (const float*)d_in[12];
  const float* bn1m = (const float*)d_in[13]; const float* bn1v = (const float*)d_in[14];
  const float* sw2  = (const float*)d_in[15]; const float* sb2 = (const float*)d_in[16];
  const float* bn2g = (const float*)d_in[17]; const float* bn2b = (const float*)d_in[18];
  const float* bn2m = (const float*)d_in[19]; const float* bn2v = (const float*)d_in[20];
  const float* cw   = (const float*)d_in[21]; const float* cb  = (const float*)d_in[22];
  const float* ew1  = (const float*)d_in[23]; const float* eb1 = (const float*)d_in[24];
  const float* ew2  = (const float*)d_in[25]; const float* eb2 = (const float*)d_in[26];
  const float* ew3  = (const float*)d_in[27]; const float* eb3 = (const float*)d_in[28];
  float* out = (float*)d_out;

  // ---- workspace layout (floats), ~157 MB ----
  float* ws = (float*)d_ws;
  size_t off = 0;
  _Float16* flat16 = (_Float16*)(ws + off); off += 147456;
  float* gsum   = ws + off; off += BATCH * 32;
  _Float16* wpk3 = (_Float16*)(ws + off); off += 9216;
  _Float16* wpk4 = (_Float16*)(ws + off); off += 36864;
  _Float16* wp2  = (_Float16*)(ws + off); off += 7680;
  _Float16* wps2 = (_Float16*)(ws + off); off += 3072;
  _Float16* wpf  = (_Float16*)(ws + off); off += 3072;
  off += 16;                                                      // guard pad
  float* bufA   = ws + off; off += 13778944;
  off += 16;                                                      // guard pad
  float* bufB   = ws + off; off += 23887872;
  off += 16;
  (void)ws_size; (void)in_sizes; (void)n_in; (void)out_size;

  _Float16* s1h = (_Float16*)bufA;
  _Float16* C3u = (_Float16*)bufA;
  _Float16* ewp1 = (_Float16*)(bufA + 6500000);
  _Float16* ewp2 = ewp1 + 3538944;
  _Float16* ewp3 = ewp2 + 1572864;
  _Float16* c1h = (_Float16*)bufB;
  _Float16* c2h = (_Float16*)(bufB + 14000000);
  _Float16* c4h = (_Float16*)bufB;
  _Float16* h1  = (_Float16*)bufB;
  _Float16* h2  = h1 + 786432;

  dim3 blk(256);

  // ---- conv weight packs + gsum zero ----
  wpackC_k<<<dim3(500), blk, 0, stream>>>(
      tw3, wpk3, tw4, wpk4, tw2, wp2, sw2, wps2, sw1, tw1, wpf, gsum);

  // ---- expert packs (first) + fused scout1+conv1 (issue-early staging) ----
  fusedX_k<<<dim3(30208), blk, 0, stream>>>(
      x, wpf, sb1, tb1, bn1g, bn1b, bn1m, bn1v, s1h, c1h,
      ew1, ewp1, ew2, ewp2, ew3, ewp3);

  // ---- merged scout2(gate-sum) + conv2(fused pool1) ----
  convSS_k<<<dim3(BATCH*28*2), blk, 0, stream>>>(
      s1h, wps2, sb2, bn2g, bn2b, bn2m, bn2v, gsum,
      c1h, wp2, tb2, c2h);

  // ---- conv3 with fused pool2 -> unpadded C3u ----
  convM_k<32,64,true><<<dim3(BATCH*14), blk, 0, stream>>>(
      c2h, wpk3, tb3, C3u);

  // ---- conv4 -> fp16 c4h ----
  convM_k<64,128,false><<<dim3(BATCH*14), blk, 0, stream>>>(
      C3u, wpk4, tb4, c4h);

  // ---- pool+adaptive-avg -> fp16 flat ----
  papool2_k<<<dim3(BATCH), blk, 0, stream>>>(c4h, flat16);

  // ---- MoE head GEMMs ----
  gemmH_k<1152,1><<<dim3(8,16,3), blk, 0, stream>>>(
      flat16, 0L, ewp1, eb1, 1024, h1);
  gemmH_k<1024,1><<<dim3(8,8,3), blk, 0, stream>>>(
      h1, 256L*1024, ewp2, eb2, 512, h2);
  gemmC_k<<<dim3(16,8), blk, 0, stream>>>(
      h2, ewp3, eb3, gsum, cw, cb, out);
}